// Round 11
// baseline (1368.163 us; speedup 1.0000x reference)
//
#include <hip/hip_runtime.h>
#include <hip/hip_fp16.h>
#include <stdint.h>

typedef __attribute__((ext_vector_type(8))) _Float16 half8;
typedef __attribute__((ext_vector_type(2))) _Float16 half2v;
typedef __attribute__((ext_vector_type(8))) short short8;
typedef __attribute__((ext_vector_type(4))) float floatx4;
typedef __attribute__((ext_vector_type(2))) float float2v;

#define K_DIM 4096
#define N_DIM 11008
#define NQ_DIM 1376
#define NT_DIM 86
#define BK 32
#define NSTEPS 128
#define BM 128
#define BN 128
#define SUPER_M 16

__device__ __forceinline__ uint32_t pkh(float a, float b) {
    half2v h; h[0] = (_Float16)a; h[1] = (_Float16)b;
    union { half2v h; uint32_t u; } c; c.h = h; return c.u;
}
__device__ __forceinline__ half2v u2h(uint32_t u) {
    union { uint32_t u; half2v h; } c; c.u = u; return c.h;
}
__device__ __forceinline__ uint32_t h2u(half2v h) {
    union { half2v h; uint32_t u; } c; c.h = h; return c.u;
}

// ---- pass 0a: x f32 -> f16 into workspace ----
__global__ __launch_bounds__(256)
void cvt_x(const float* __restrict__ x, unsigned short* __restrict__ xb, int n8) {
    int i = blockIdx.x * 256 + threadIdx.x;
    const int stride = gridDim.x * 256;
    for (; i < n8; i += stride) {
        floatx4 a = *(const floatx4*)(x + (size_t)i * 8);
        floatx4 b = *(const floatx4*)(x + (size_t)i * 8 + 4);
        union { short8 v; uint32_t u[4]; } o;
        o.u[0] = pkh(a[0], a[1]);
        o.u[1] = pkh(a[2], a[3]);
        o.u[2] = pkh(b[0], b[1]);
        o.u[3] = pkh(b[2], b[3]);
        *(short8*)(xb + (size_t)i * 8) = o.v;
    }
}

// ---- pass 0b: dequantize W once into FRAGMENT-layout f16 image ----
// wb region (nt, t): 8192 B = [col=128][kb=4][k8=8] f16; k = t*32+kb*8+k8, n = nt*128+col.
// A wave's B-fragment j read (col = wn + j*16 + lm, kb = kb_l) is then exactly
// lane-linear: addr = lane*16B within a 1KB span -> perfect coalescing.
__global__ __launch_bounds__(256)
void deq_w(const int* __restrict__ qweight, const int* __restrict__ qzeros,
           const float* __restrict__ scales, unsigned short* __restrict__ wb) {
    const int nt = blockIdx.x;          // 0..85
    const int t  = blockIdx.y;          // 0..127 (K-step)
    const int c  = threadIdx.x & 127;   // local col
    const int kh = threadIdx.x >> 7;    // 0/1 -> kb pair
    const int g  = t >> 2;              // group
    const int col  = nt * 128 + c;
    const int sh   = ((c & 1) ? 16 : 0) + ((c & 7) >> 1) * 4;   // AWQ inverse order
    const int word = nt * 16 + (c >> 3);

    const uint32_t zw = (uint32_t)qzeros[(size_t)g * NQ_DIM + word];
    const uint32_t zn = ((zw >> sh) & 0xFu) | 0x6400u;          // 1024 + z
    const half2v zt = u2h(zn | (zn << 16));
    const float s = scales[(size_t)g * N_DIM + col];
    half2v st; st[0] = (_Float16)s; st[1] = (_Float16)s;

    const int* qp = qweight + (size_t)(t * 32 + kh * 16) * NQ_DIM + word;
    unsigned short* wt = wb + ((size_t)nt * 128 + t) * 4096;

#pragma unroll
    for (int h = 0; h < 2; ++h) {                               // kb = kh*2 + h
        union { half8 v; uint32_t u[4]; } o;
#pragma unroll
        for (int p = 0; p < 4; ++p) {
            const uint32_t qa = (uint32_t)qp[(size_t)(h * 8 + 2 * p)     * NQ_DIM];
            const uint32_t qb = (uint32_t)qp[(size_t)(h * 8 + 2 * p + 1) * NQ_DIM];
            uint32_t u = ((qa >> sh) & 0xFu) | (((qb >> sh) & 0xFu) << 16) | 0x64006400u;
            o.u[p] = h2u((u2h(u) - zt) * st);                   // exact int sub, fp16 mul
        }
        *(half8*)(wt + (size_t)((c * 4 + kh * 2 + h) * 8)) = o.v;   // [col][kb][k8]
    }
}

// ---- main GEMM: BM=128 x BN=128, BK=32, 256 thr (4 waves 2Mx2N) ----
// A: LDS double-buffer via global_load_lds ([kb=4][row=128][8k], 8KB/buf).
// B: DIRECT from global wb into registers, double-buffered (no LDS).
__global__ __launch_bounds__(256, 3)
void awq_gemm7(const unsigned short* __restrict__ xb,
               const unsigned short* __restrict__ wb,
               const float* __restrict__ bias,
               float* __restrict__ out)
{
    __shared__ char lds[16384] __attribute__((aligned(128)));

    const int tid  = threadIdx.x;
    const int lane = tid & 63;
    const int wid  = tid >> 6;

    // super-tile swizzle (m-fastest in super-rows of 16 m-tiles)
    const int flat = blockIdx.y * NT_DIM + blockIdx.x;
    const int per_super = NT_DIM * SUPER_M;
    const int s  = flat / per_super;
    const int r  = flat % per_super;
    const int nt = r >> 4;
    const int mt = (s << 4) + (r & (SUPER_M - 1));
    const int n0 = nt * BN;
    const int m0 = mt * BM;

    // A staging: wave wid stages kb=wid; lane-linear 16B (full 8-k slice per row)
    const unsigned short* agl0 = xb + (size_t)(m0 + lane) * K_DIM + wid * 8;
    const unsigned short* agl1 = xb + (size_t)(m0 + 64 + lane) * K_DIM + wid * 8;

    // fragment geometry
    const int wm = (wid >> 1) * 64;
    const int wn = (wid & 1) * 64;
    const int lm = lane & 15;
    const int kb_l = lane >> 4;
    const int aoff = kb_l * 2048 + (wm + lm) * 16;       // + i*256

    // B direct-load base: frag j at + j*512 halfs; step t at + t*4096 halfs
    const unsigned short* bgl = wb + (size_t)nt * 524288 + ((wn + lm) * 4 + kb_l) * 8;

    floatx4 acc[4][4];
#pragma unroll
    for (int i = 0; i < 4; ++i)
#pragma unroll
        for (int j = 0; j < 4; ++j)
            acc[i][j] = (floatx4){0.f, 0.f, 0.f, 0.f};

    half8 b0[4], b1[4];

    auto stageA = [&](int dbuf) {
        const int ab = dbuf * 8192;
        __builtin_amdgcn_global_load_lds(
            (const __attribute__((address_space(1))) void*)agl0,
            (__attribute__((address_space(3))) void*)(&lds[ab + wid * 2048]), 16, 0, 0);
        __builtin_amdgcn_global_load_lds(
            (const __attribute__((address_space(1))) void*)agl1,
            (__attribute__((address_space(3))) void*)(&lds[ab + wid * 2048 + 1024]), 16, 0, 0);
        agl0 += BK; agl1 += BK;
    };
    auto loadB = [&](half8* b) {
#pragma unroll
        for (int j = 0; j < 4; ++j)
            b[j] = *(const half8*)(bgl + j * 512);
        bgl += 4096;
    };
    auto compute = [&](int dbuf, const half8* b) {
        const int ab = dbuf * 8192;
        half8 af[4];
#pragma unroll
        for (int i = 0; i < 4; ++i) af[i] = *(const half8*)&lds[ab + aoff + i * 256];
#pragma unroll
        for (int i = 0; i < 4; ++i)
#pragma unroll
            for (int j = 0; j < 4; ++j)
                acc[i][j] = __builtin_amdgcn_mfma_f32_16x16x32_f16(af[i], b[j], acc[i][j], 0, 0, 0);
    };

    // prologue: tile 0
    stageA(0);
    loadB(b0);
    __syncthreads();

    for (int t = 0; t < NSTEPS; t += 2) {
        stageA(1);                        // A(t+1)
        loadB(b1);                        // B(t+1)
        compute(0, b0);                   // tile t
        __syncthreads();
        if (t + 2 < NSTEPS) {
            stageA(0);                    // A(t+2)
            loadB(b0);                    // B(t+2)
        }
        compute(1, b1);                   // tile t+1
        __syncthreads();
    }

    // epilogue: C/D col = lane&15, row = (lane>>4)*4 + r ; non-temporal stores
    const int colb = n0 + wn + lm;
    const int rowb = m0 + wm + (kb_l << 2);
#pragma unroll
    for (int j = 0; j < 4; ++j) {
        const int col = colb + j * 16;
        const float bias_f = bias[col];
#pragma unroll
        for (int i = 0; i < 4; ++i) {
            const int row = rowb + i * 16;
#pragma unroll
            for (int r4 = 0; r4 < 4; ++r4) {
                __builtin_nontemporal_store(acc[i][j][r4] + bias_f,
                                            &out[(size_t)(row + r4) * N_DIM + col]);
            }
        }
    }
}

// ================= R8 fused kernel (fallback when ws too small) =================
template <bool PRECVT>
__global__ __launch_bounds__(256, 3)
void awq_gemm5(const float* __restrict__ xf,
               const unsigned short* __restrict__ xb,
               const int* __restrict__ qweight,
               const int* __restrict__ qzeros,
               const float* __restrict__ scales,
               const float* __restrict__ bias,
               float* __restrict__ out)
{
    __shared__ char lds[32768] __attribute__((aligned(128)));
    const int tid  = threadIdx.x;
    const int lane = tid & 63;
    const int wid  = tid >> 6;
    const int n0 = blockIdx.x * BN;
    const int m0 = blockIdx.y * BM;

    const unsigned short* agl0 = xb + (size_t)(m0 + lane) * K_DIM + wid * 8;
    const unsigned short* agl1 = xb + (size_t)(m0 + 64 + lane) * K_DIM + wid * 8;
    const float* aptr = xf + (size_t)(m0 + (tid >> 1)) * K_DIM + (tid & 1) * 16;
    const int awr = ((tid & 1) * 2) * 2048 + (tid >> 1) * 16;

    const int nq      = tid & 15;
    const int k_local = (tid >> 4) * 2;
    const int kb_w    = k_local >> 3;
    const int k8      = k_local & 7;
    const int nq7     = nq & 7;
    const int* qp0 = qweight + blockIdx.x * 16 + nq + (size_t)k_local * NQ_DIM;
    const int* qp1 = qp0 + NQ_DIM;
    const int* zp  = qzeros + blockIdx.x * 16 + nq;
    const float* sp = scales + n0 + nq * 8;
    int baddr[8];
#pragma unroll
    for (int j = 0; j < 8; ++j)
        baddr[j] = 16384 + (kb_w * 128 + nq * 8 + (j ^ nq7)) * 16 + k8 * 2;

    const int wm = (wid >> 1) * 64;
    const int wn = (wid & 1) * 64;
    const int lm = lane & 15;
    const int kb_l = lane >> 4;
    const int aoff = kb_l * 2048 + (wm + lm) * 16;
    int boff[4];
#pragma unroll
    for (int j = 0; j < 4; ++j) {
        int blk = kb_l * 128 + wn + j * 16 + lm;
        blk ^= (blk >> 3) & 7;
        boff[j] = 16384 + blk * 16;
    }

    floatx4 acc[4][4];
#pragma unroll
    for (int i = 0; i < 4; ++i)
#pragma unroll
        for (int j = 0; j < 4; ++j)
            acc[i][j] = (floatx4){0.f, 0.f, 0.f, 0.f};

    half2v zt[4], st[4];
    uint32_t q0, q1;

    auto stage_a = [&](int abase) {
        if constexpr (PRECVT) {
            __builtin_amdgcn_global_load_lds(
                (const __attribute__((address_space(1))) void*)agl0,
                (__attribute__((address_space(3))) void*)(&lds[abase + wid * 2048]), 16, 0, 0);
            __builtin_amdgcn_global_load_lds(
                (const __attribute__((address_space(1))) void*)agl1,
                (__attribute__((address_space(3))) void*)(&lds[abase + wid * 2048 + 1024]), 16, 0, 0);
            agl0 += BK; agl1 += BK;
        } else {
            floatx4 a0 = *(const floatx4*)(aptr + 0);
            floatx4 a1 = *(const floatx4*)(aptr + 4);
            floatx4 a2 = *(const floatx4*)(aptr + 8);
            floatx4 a3 = *(const floatx4*)(aptr + 12);
            aptr += BK;
            union { short8 v; uint32_t u[4]; } o0, o1;
            o0.u[0] = pkh(a0[0], a0[1]); o0.u[1] = pkh(a0[2], a0[3]);
            o0.u[2] = pkh(a1[0], a1[1]); o0.u[3] = pkh(a1[2], a1[3]);
            o1.u[0] = pkh(a2[0], a2[1]); o1.u[1] = pkh(a2[2], a2[3]);
            o1.u[2] = pkh(a3[0], a3[1]); o1.u[3] = pkh(a3[2], a3[3]);
            *(short8*)&lds[abase + awr]        = o0.v;
            *(short8*)&lds[abase + awr + 2048] = o1.v;
        }
    };
    auto load_q = [&]() {
        q0 = (uint32_t)*qp0; q1 = (uint32_t)*qp1;
        qp0 += (size_t)BK * NQ_DIM; qp1 += (size_t)BK * NQ_DIM;
    };
    auto refresh = [&]() {
        const uint32_t zw = (uint32_t)*zp;
        zp += NQ_DIM;
#pragma unroll
        for (int l = 0; l < 4; ++l) {
            zt[l] = u2h(((zw >> (4 * l)) & 0x000F000Fu) | 0x64006400u);
            float2v s2 = *(const float2v*)(sp + 2 * l);
            half2v sh2; sh2[0] = (_Float16)s2[0]; sh2[1] = (_Float16)s2[1];
            st[l] = sh2;
        }
        sp += N_DIM;
    };
    auto deq_store = [&](int off) {
#pragma unroll
        for (int l = 0; l < 4; ++l) {
            uint32_t t0 = ((q0 >> (4 * l)) & 0x000F000Fu) | 0x64006400u;
            uint32_t t1 = ((q1 >> (4 * l)) & 0x000F000Fu) | 0x64006400u;
            half2v w0 = (u2h(t0) - zt[l]) * st[l];
            half2v w1 = (u2h(t1) - zt[l]) * st[l];
            uint32_t p0 = h2u(w0), p1 = h2u(w1);
            uint32_t de = (p0 & 0xFFFFu) | (p1 << 16);
            uint32_t dd = (p0 >> 16) | (p1 & 0xFFFF0000u);
            *(uint32_t*)&lds[baddr[2 * l]     + off] = de;
            *(uint32_t*)&lds[baddr[2 * l + 1] + off] = dd;
        }
    };
    auto compute = [&](int ab, int bb) {
        half8 af[4], bfr[4];
#pragma unroll
        for (int i = 0; i < 4; ++i) af[i] = *(const half8*)&lds[ab + aoff + i * 256];
#pragma unroll
        for (int j = 0; j < 4; ++j) bfr[j] = *(const half8*)&lds[bb + boff[j] - 16384];
#pragma unroll
        for (int i = 0; i < 4; ++i)
#pragma unroll
            for (int j = 0; j < 4; ++j)
                acc[i][j] = __builtin_amdgcn_mfma_f32_16x16x32_f16(af[i], bfr[j], acc[i][j], 0, 0, 0);
    };

    stage_a(0); load_q(); refresh(); deq_store(0); load_q();
    __syncthreads();

    for (int t = 0; t < NSTEPS; t += 2) {
        stage_a(8192);
        deq_store(8192);
        if (t + 2 < NSTEPS) load_q();
        compute(0, 16384);
        __syncthreads();
        if (t + 2 < NSTEPS) {
            stage_a(0);
            if (((t + 2) & 3) == 0) refresh();
            deq_store(0);
            if (t + 3 < NSTEPS) load_q();
        }
        compute(8192, 24576);
        __syncthreads();
    }

    const int colb = n0 + wn + lm;
    const int rowb = m0 + wm + (kb_l << 2);
#pragma unroll
    for (int j = 0; j < 4; ++j) {
        const int col = colb + j * 16;
        const float bias_f = bias[col];
#pragma unroll
        for (int i = 0; i < 4; ++i) {
            const int row = rowb + i * 16;
#pragma unroll
            for (int r4 = 0; r4 < 4; ++r4) {
                out[(size_t)(row + r4) * N_DIM + col] = acc[i][j][r4] + bias_f;
            }
        }
    }
}

extern "C" void kernel_launch(void* const* d_in, const int* in_sizes, int n_in,
                              void* d_out, int out_size, void* d_ws, size_t ws_size,
                              hipStream_t stream) {
    const float* x    = (const float*)d_in[0];
    const int* qw     = (const int*)d_in[1];
    const int* qz     = (const int*)d_in[2];
    const float* sc   = (const float*)d_in[3];
    const float* bi   = (const float*)d_in[4];
    float* out        = (float*)d_out;

    const int M = in_sizes[0] / K_DIM;                       // 8192
    const size_t xb_bytes = (size_t)M * K_DIM * 2;           // 64 MiB
    const size_t wb_bytes = (size_t)K_DIM * N_DIM * 2;       // 86 MiB
    dim3 grid(N_DIM / BN, M / BM);                           // (86, 64)

    if (ws_size >= xb_bytes + wb_bytes) {
        unsigned short* xb = (unsigned short*)d_ws;
        unsigned short* wb = (unsigned short*)((char*)d_ws + xb_bytes);
        const int n8 = (int)((size_t)M * K_DIM / 8);
        cvt_x<<<2048, 256, 0, stream>>>(x, xb, n8);
        deq_w<<<dim3(NT_DIM, NSTEPS), 256, 0, stream>>>(qw, qz, sc, wb);
        awq_gemm7<<<grid, 256, 0, stream>>>(xb, wb, bi, out);
    } else if (ws_size >= xb_bytes) {
        unsigned short* xb = (unsigned short*)d_ws;
        const int n8 = (int)((size_t)M * K_DIM / 8);
        cvt_x<<<2048, 256, 0, stream>>>(x, xb, n8);
        awq_gemm5<true><<<grid, 256, 0, stream>>>(x, xb, qw, qz, sc, bi, out);
    } else {
        awq_gemm5<false><<<grid, 256, 0, stream>>>(x, nullptr, qw, qz, sc, bi, out);
    }
}

// Round 12
// 1030.908 us; speedup vs baseline: 1.3271x; 1.3271x over previous
//
#include <hip/hip_runtime.h>
#include <hip/hip_fp16.h>
#include <stdint.h>

typedef __attribute__((ext_vector_type(8))) _Float16 half8;
typedef __attribute__((ext_vector_type(2))) _Float16 half2v;
typedef __attribute__((ext_vector_type(8))) short short8;
typedef __attribute__((ext_vector_type(4))) float floatx4;
typedef __attribute__((ext_vector_type(2))) float float2v;

#define K_DIM 4096
#define N_DIM 11008
#define NQ_DIM 1376
#define NT_DIM 86
#define BK 32
#define NSTEPS 128
#define BM 128
#define BN 128
#define SUPER_M 16

__device__ __forceinline__ uint32_t pkh(float a, float b) {
    half2v h; h[0] = (_Float16)a; h[1] = (_Float16)b;
    union { half2v h; uint32_t u; } c; c.h = h; return c.u;
}
__device__ __forceinline__ half2v u2h(uint32_t u) {
    union { uint32_t u; half2v h; } c; c.u = u; return c.h;
}
__device__ __forceinline__ uint32_t h2u(half2v h) {
    union { half2v h; uint32_t u; } c; c.h = h; return c.u;
}

// ---- pass 0a: x f32 -> f16 into workspace ----
__global__ __launch_bounds__(256)
void cvt_x(const float* __restrict__ x, unsigned short* __restrict__ xb, int n8) {
    int i = blockIdx.x * 256 + threadIdx.x;
    const int stride = gridDim.x * 256;
    for (; i < n8; i += stride) {
        floatx4 a = *(const floatx4*)(x + (size_t)i * 8);
        floatx4 b = *(const floatx4*)(x + (size_t)i * 8 + 4);
        union { short8 v; uint32_t u[4]; } o;
        o.u[0] = pkh(a[0], a[1]);
        o.u[1] = pkh(a[2], a[3]);
        o.u[2] = pkh(b[0], b[1]);
        o.u[3] = pkh(b[2], b[3]);
        *(short8*)(xb + (size_t)i * 8) = o.v;
    }
}

// ---- pass 0b: dequantize W once into tiled f16 image (R10 layout) ----
// wb region (nt, t): 8192 B = [kb=4][col=128][k8=8] f16; k = t*32+kb*8+k8, n = nt*128+col.
__global__ __launch_bounds__(256)
void deq_w(const int* __restrict__ qweight, const int* __restrict__ qzeros,
           const float* __restrict__ scales, unsigned short* __restrict__ wb) {
    const int nt = blockIdx.x;          // 0..85
    const int t  = blockIdx.y;          // 0..127 (K-step)
    const int c  = threadIdx.x & 127;   // local col
    const int kh = threadIdx.x >> 7;    // 0/1 -> kb pair
    const int g  = t >> 2;              // group
    const int col  = nt * 128 + c;
    const int sh   = ((c & 1) ? 16 : 0) + ((c & 7) >> 1) * 4;   // AWQ inverse order
    const int word = nt * 16 + (c >> 3);

    const uint32_t zw = (uint32_t)qzeros[(size_t)g * NQ_DIM + word];
    const uint32_t zn = ((zw >> sh) & 0xFu) | 0x6400u;          // 1024 + z
    const half2v zt = u2h(zn | (zn << 16));
    const float s = scales[(size_t)g * N_DIM + col];
    half2v st; st[0] = (_Float16)s; st[1] = (_Float16)s;

    const int* qp = qweight + (size_t)(t * 32 + kh * 16) * NQ_DIM + word;
    unsigned short* wt = wb + ((size_t)nt * 128 + t) * 4096;

#pragma unroll
    for (int h = 0; h < 2; ++h) {                               // kb = kh*2 + h
        union { half8 v; uint32_t u[4]; } o;
#pragma unroll
        for (int p = 0; p < 4; ++p) {
            const uint32_t qa = (uint32_t)qp[(size_t)(h * 8 + 2 * p)     * NQ_DIM];
            const uint32_t qb = (uint32_t)qp[(size_t)(h * 8 + 2 * p + 1) * NQ_DIM];
            uint32_t u = ((qa >> sh) & 0xFu) | (((qb >> sh) & 0xFu) << 16) | 0x64006400u;
            o.u[p] = h2u((u2h(u) - zt) * st);                   // exact int sub, fp16 mul
        }
        *(half8*)(wt + (size_t)(((kh * 2 + h) * 128 + c) * 8)) = o.v;
    }
}

// ---- main GEMM: R10 structure + counted-vmcnt pipeline (T3/T4 minimum) ----
// LDS: A buf0 [0,8K), A buf1 [8K,16K) : [kb=4][row=128][8k] f16
//      B buf0 [16K,24K), B buf1 [24K,32K): [kb=4][col=128][8k] f16 (= wb image)
// Per K-step: vmcnt(4) [prev tile done, next tile's 4 loads stay IN FLIGHT]
//             -> s_barrier -> compute -> s_barrier -> stage(t+2).
__global__ __launch_bounds__(256, 3)
void awq_gemm8(const unsigned short* __restrict__ xb,
               const unsigned short* __restrict__ wb,
               const float* __restrict__ bias,
               float* __restrict__ out)
{
    __shared__ char lds[32768] __attribute__((aligned(128)));

    const int tid  = threadIdx.x;
    const int lane = tid & 63;
    const int wid  = tid >> 6;

    // super-tile swizzle (m-fastest in super-rows of 16 m-tiles)
    const int flat = blockIdx.y * NT_DIM + blockIdx.x;
    const int per_super = NT_DIM * SUPER_M;
    const int s  = flat / per_super;
    const int r  = flat % per_super;
    const int nt = r >> 4;
    const int mt = (s << 4) + (r & (SUPER_M - 1));
    const int n0 = nt * BN;
    const int m0 = mt * BM;

    // A staging: wave wid stages kb=wid; lane-linear 16B (full 8-k slice per row)
    const unsigned short* agl0 = xb + (size_t)(m0 + lane) * K_DIM + wid * 8;
    const unsigned short* agl1 = xb + (size_t)(m0 + 64 + lane) * K_DIM + wid * 8;
    // B staging: linear copy of the 8KB tile image; per wave 2KB
    const unsigned short* wbp = wb + ((size_t)nt * 128) * 4096 + wid * 1024 + lane * 8;

    // fragment read offsets (within-buf)
    const int wm = (wid >> 1) * 64;
    const int wn = (wid & 1) * 64;
    const int lm = lane & 15;
    const int kb_l = lane >> 4;
    const int aoff = kb_l * 2048 + (wm + lm) * 16;       // + i*256
    const int boff = kb_l * 2048 + (wn + lm) * 16;       // + j*256

    floatx4 acc[4][4];
#pragma unroll
    for (int i = 0; i < 4; ++i)
#pragma unroll
        for (int j = 0; j < 4; ++j)
            acc[i][j] = (floatx4){0.f, 0.f, 0.f, 0.f};

    auto stage = [&](int dbuf) {
        const int ab = dbuf * 8192;
        const int bb = 16384 + dbuf * 8192;
        __builtin_amdgcn_global_load_lds(
            (const __attribute__((address_space(1))) void*)agl0,
            (__attribute__((address_space(3))) void*)(&lds[ab + wid * 2048]), 16, 0, 0);
        __builtin_amdgcn_global_load_lds(
            (const __attribute__((address_space(1))) void*)agl1,
            (__attribute__((address_space(3))) void*)(&lds[ab + wid * 2048 + 1024]), 16, 0, 0);
        __builtin_amdgcn_global_load_lds(
            (const __attribute__((address_space(1))) void*)wbp,
            (__attribute__((address_space(3))) void*)(&lds[bb + wid * 2048]), 16, 0, 0);
        __builtin_amdgcn_global_load_lds(
            (const __attribute__((address_space(1))) void*)(wbp + 512),
            (__attribute__((address_space(3))) void*)(&lds[bb + wid * 2048 + 1024]), 16, 0, 0);
        agl0 += BK; agl1 += BK; wbp += 4096;
    };
    auto compute = [&](int dbuf) {
        const int ab = dbuf * 8192;
        const int bb = 16384 + dbuf * 8192;
        half8 af[4], bf[4];
#pragma unroll
        for (int i = 0; i < 4; ++i) af[i] = *(const half8*)&lds[ab + aoff + i * 256];
#pragma unroll
        for (int j = 0; j < 4; ++j) bf[j] = *(const half8*)&lds[bb + boff + j * 256];
#pragma unroll
        for (int i = 0; i < 4; ++i)
#pragma unroll
            for (int j = 0; j < 4; ++j)
                acc[i][j] = __builtin_amdgcn_mfma_f32_16x16x32_f16(af[i], bf[j], acc[i][j], 0, 0, 0);
    };

    // prologue: two tiles in flight
    stage(0);          // tile 0
    stage(1);          // tile 1

    for (int t = 0; t < NSTEPS - 2; t += 2) {
        // ---- step t (buf0) ----
        asm volatile("s_waitcnt vmcnt(4)" ::: "memory");   // tile t done; t+1 in flight
        __builtin_amdgcn_s_barrier();
        __builtin_amdgcn_sched_barrier(0);
        compute(0);
        __builtin_amdgcn_sched_barrier(0);
        __builtin_amdgcn_s_barrier();
        stage(0);                                          // tile t+2
        // ---- step t+1 (buf1) ----
        asm volatile("s_waitcnt vmcnt(4)" ::: "memory");   // tile t+1 done; t+2 in flight
        __builtin_amdgcn_s_barrier();
        __builtin_amdgcn_sched_barrier(0);
        compute(1);
        __builtin_amdgcn_sched_barrier(0);
        __builtin_amdgcn_s_barrier();
        stage(1);                                          // tile t+3
    }

    // tail: tiles NSTEPS-2 (buf0), NSTEPS-1 (buf1)
    asm volatile("s_waitcnt vmcnt(4)" ::: "memory");
    __builtin_amdgcn_s_barrier();
    __builtin_amdgcn_sched_barrier(0);
    compute(0);
    asm volatile("s_waitcnt vmcnt(0)" ::: "memory");
    __builtin_amdgcn_s_barrier();
    __builtin_amdgcn_sched_barrier(0);
    compute(1);

    // epilogue: C/D col = lane&15, row = (lane>>4)*4 + r ; non-temporal stores
    const int colb = n0 + wn + lm;
    const int rowb = m0 + wm + (kb_l << 2);
#pragma unroll
    for (int j = 0; j < 4; ++j) {
        const int col = colb + j * 16;
        const float bias_f = bias[col];
#pragma unroll
        for (int i = 0; i < 4; ++i) {
            const int row = rowb + i * 16;
#pragma unroll
            for (int r4 = 0; r4 < 4; ++r4) {
                __builtin_nontemporal_store(acc[i][j][r4] + bias_f,
                                            &out[(size_t)(row + r4) * N_DIM + col]);
            }
        }
    }
}

// ================= R8 fused kernel (fallback when ws too small) =================
template <bool PRECVT>
__global__ __launch_bounds__(256, 3)
void awq_gemm5(const float* __restrict__ xf,
               const unsigned short* __restrict__ xb,
               const int* __restrict__ qweight,
               const int* __restrict__ qzeros,
               const float* __restrict__ scales,
               const float* __restrict__ bias,
               float* __restrict__ out)
{
    __shared__ char lds[32768] __attribute__((aligned(128)));
    const int tid  = threadIdx.x;
    const int lane = tid & 63;
    const int wid  = tid >> 6;
    const int n0 = blockIdx.x * BN;
    const int m0 = blockIdx.y * BM;

    const unsigned short* agl0 = xb + (size_t)(m0 + lane) * K_DIM + wid * 8;
    const unsigned short* agl1 = xb + (size_t)(m0 + 64 + lane) * K_DIM + wid * 8;
    const float* aptr = xf + (size_t)(m0 + (tid >> 1)) * K_DIM + (tid & 1) * 16;
    const int awr = ((tid & 1) * 2) * 2048 + (tid >> 1) * 16;

    const int nq      = tid & 15;
    const int k_local = (tid >> 4) * 2;
    const int kb_w    = k_local >> 3;
    const int k8      = k_local & 7;
    const int nq7     = nq & 7;
    const int* qp0 = qweight + blockIdx.x * 16 + nq + (size_t)k_local * NQ_DIM;
    const int* qp1 = qp0 + NQ_DIM;
    const int* zp  = qzeros + blockIdx.x * 16 + nq;
    const float* sp = scales + n0 + nq * 8;
    int baddr[8];
#pragma unroll
    for (int j = 0; j < 8; ++j)
        baddr[j] = 16384 + (kb_w * 128 + nq * 8 + (j ^ nq7)) * 16 + k8 * 2;

    const int wm = (wid >> 1) * 64;
    const int wn = (wid & 1) * 64;
    const int lm = lane & 15;
    const int kb_l = lane >> 4;
    const int aoff = kb_l * 2048 + (wm + lm) * 16;
    int boff[4];
#pragma unroll
    for (int j = 0; j < 4; ++j) {
        int blk = kb_l * 128 + wn + j * 16 + lm;
        blk ^= (blk >> 3) & 7;
        boff[j] = 16384 + blk * 16;
    }

    floatx4 acc[4][4];
#pragma unroll
    for (int i = 0; i < 4; ++i)
#pragma unroll
        for (int j = 0; j < 4; ++j)
            acc[i][j] = (floatx4){0.f, 0.f, 0.f, 0.f};

    half2v zt[4], st[4];
    uint32_t q0, q1;

    auto stage_a = [&](int abase) {
        if constexpr (PRECVT) {
            __builtin_amdgcn_global_load_lds(
                (const __attribute__((address_space(1))) void*)agl0,
                (__attribute__((address_space(3))) void*)(&lds[abase + wid * 2048]), 16, 0, 0);
            __builtin_amdgcn_global_load_lds(
                (const __attribute__((address_space(1))) void*)agl1,
                (__attribute__((address_space(3))) void*)(&lds[abase + wid * 2048 + 1024]), 16, 0, 0);
            agl0 += BK; agl1 += BK;
        } else {
            floatx4 a0 = *(const floatx4*)(aptr + 0);
            floatx4 a1 = *(const floatx4*)(aptr + 4);
            floatx4 a2 = *(const floatx4*)(aptr + 8);
            floatx4 a3 = *(const floatx4*)(aptr + 12);
            aptr += BK;
            union { short8 v; uint32_t u[4]; } o0, o1;
            o0.u[0] = pkh(a0[0], a0[1]); o0.u[1] = pkh(a0[2], a0[3]);
            o0.u[2] = pkh(a1[0], a1[1]); o0.u[3] = pkh(a1[2], a1[3]);
            o1.u[0] = pkh(a2[0], a2[1]); o1.u[1] = pkh(a2[2], a2[3]);
            o1.u[2] = pkh(a3[0], a3[1]); o1.u[3] = pkh(a3[2], a3[3]);
            *(short8*)&lds[abase + awr]        = o0.v;
            *(short8*)&lds[abase + awr + 2048] = o1.v;
        }
    };
    auto load_q = [&]() {
        q0 = (uint32_t)*qp0; q1 = (uint32_t)*qp1;
        qp0 += (size_t)BK * NQ_DIM; qp1 += (size_t)BK * NQ_DIM;
    };
    auto refresh = [&]() {
        const uint32_t zw = (uint32_t)*zp;
        zp += NQ_DIM;
#pragma unroll
        for (int l = 0; l < 4; ++l) {
            zt[l] = u2h(((zw >> (4 * l)) & 0x000F000Fu) | 0x64006400u);
            float2v s2 = *(const float2v*)(sp + 2 * l);
            half2v sh2; sh2[0] = (_Float16)s2[0]; sh2[1] = (_Float16)s2[1];
            st[l] = sh2;
        }
        sp += N_DIM;
    };
    auto deq_store = [&](int off) {
#pragma unroll
        for (int l = 0; l < 4; ++l) {
            uint32_t t0 = ((q0 >> (4 * l)) & 0x000F000Fu) | 0x64006400u;
            uint32_t t1 = ((q1 >> (4 * l)) & 0x000F000Fu) | 0x64006400u;
            half2v w0 = (u2h(t0) - zt[l]) * st[l];
            half2v w1 = (u2h(t1) - zt[l]) * st[l];
            uint32_t p0 = h2u(w0), p1 = h2u(w1);
            uint32_t de = (p0 & 0xFFFFu) | (p1 << 16);
            uint32_t dd = (p0 >> 16) | (p1 & 0xFFFF0000u);
            *(uint32_t*)&lds[baddr[2 * l]     + off] = de;
            *(uint32_t*)&lds[baddr[2 * l + 1] + off] = dd;
        }
    };
    auto compute = [&](int ab, int bb) {
        half8 af[4], bfr[4];
#pragma unroll
        for (int i = 0; i < 4; ++i) af[i] = *(const half8*)&lds[ab + aoff + i * 256];
#pragma unroll
        for (int j = 0; j < 4; ++j) bfr[j] = *(const half8*)&lds[bb + boff[j] - 16384];
#pragma unroll
        for (int i = 0; i < 4; ++i)
#pragma unroll
            for (int j = 0; j < 4; ++j)
                acc[i][j] = __builtin_amdgcn_mfma_f32_16x16x32_f16(af[i], bfr[j], acc[i][j], 0, 0, 0);
    };

    stage_a(0); load_q(); refresh(); deq_store(0); load_q();
    __syncthreads();

    for (int t = 0; t < NSTEPS; t += 2) {
        stage_a(8192);
        deq_store(8192);
        if (t + 2 < NSTEPS) load_q();
        compute(0, 16384);
        __syncthreads();
        if (t + 2 < NSTEPS) {
            stage_a(0);
            if (((t + 2) & 3) == 0) refresh();
            deq_store(0);
            if (t + 3 < NSTEPS) load_q();
        }
        compute(8192, 24576);
        __syncthreads();
    }

    const int colb = n0 + wn + lm;
    const int rowb = m0 + wm + (kb_l << 2);
#pragma unroll
    for (int j = 0; j < 4; ++j) {
        const int col = colb + j * 16;
        const float bias_f = bias[col];
#pragma unroll
        for (int i = 0; i < 4; ++i) {
            const int row = rowb + i * 16;
#pragma unroll
            for (int r4 = 0; r4 < 4; ++r4) {
                out[(size_t)(row + r4) * N_DIM + col] = acc[i][j][r4] + bias_f;
            }
        }
    }
}

extern "C" void kernel_launch(void* const* d_in, const int* in_sizes, int n_in,
                              void* d_out, int out_size, void* d_ws, size_t ws_size,
                              hipStream_t stream) {
    const float* x    = (const float*)d_in[0];
    const int* qw     = (const int*)d_in[1];
    const int* qz     = (const int*)d_in[2];
    const float* sc   = (const float*)d_in[3];
    const float* bi   = (const float*)d_in[4];
    float* out        = (float*)d_out;

    const int M = in_sizes[0] / K_DIM;                       // 8192
    const size_t xb_bytes = (size_t)M * K_DIM * 2;           // 64 MiB
    const size_t wb_bytes = (size_t)K_DIM * N_DIM * 2;       // 86 MiB
    dim3 grid(N_DIM / BN, M / BM);                           // (86, 64)

    if (ws_size >= xb_bytes + wb_bytes) {
        unsigned short* xb = (unsigned short*)d_ws;
        unsigned short* wb = (unsigned short*)((char*)d_ws + xb_bytes);
        const int n8 = (int)((size_t)M * K_DIM / 8);
        cvt_x<<<2048, 256, 0, stream>>>(x, xb, n8);
        deq_w<<<dim3(NT_DIM, NSTEPS), 256, 0, stream>>>(qw, qz, sc, wb);
        awq_gemm8<<<grid, 256, 0, stream>>>(xb, wb, bi, out);
    } else if (ws_size >= xb_bytes) {
        unsigned short* xb = (unsigned short*)d_ws;
        const int n8 = (int)((size_t)M * K_DIM / 8);
        cvt_x<<<2048, 256, 0, stream>>>(x, xb, n8);
        awq_gemm5<true><<<grid, 256, 0, stream>>>(x, xb, qw, qz, sc, bi, out);
    } else {
        awq_gemm5<false><<<grid, 256, 0, stream>>>(x, nullptr, qw, qz, sc, bi, out);
    }
}

// Round 13
// 940.613 us; speedup vs baseline: 1.4545x; 1.0960x over previous
//
#include <hip/hip_runtime.h>
#include <hip/hip_fp16.h>
#include <stdint.h>

typedef __attribute__((ext_vector_type(8))) _Float16 half8;
typedef __attribute__((ext_vector_type(2))) _Float16 half2v;
typedef __attribute__((ext_vector_type(8))) short short8;
typedef __attribute__((ext_vector_type(4))) float floatx4;
typedef __attribute__((ext_vector_type(2))) float float2v;

#define K_DIM 4096
#define N_DIM 11008
#define NQ_DIM 1376
#define NSTEPS 128
#define BK 32
// 256x256 kernel geometry
#define NT2 43
#define SUPER2 8
// fallback 128x128 geometry
#define BM 128
#define BN 128
#define NT_DIM 86

__device__ __forceinline__ uint32_t pkh(float a, float b) {
    half2v h; h[0] = (_Float16)a; h[1] = (_Float16)b;
    union { half2v h; uint32_t u; } c; c.h = h; return c.u;
}
__device__ __forceinline__ half2v u2h(uint32_t u) {
    union { uint32_t u; half2v h; } c; c.u = u; return c.h;
}
__device__ __forceinline__ uint32_t h2u(half2v h) {
    union { half2v h; uint32_t u; } c; c.h = h; return c.u;
}

// ---- pass 0a: x f32 -> f16 ----
__global__ __launch_bounds__(256)
void cvt_x(const float* __restrict__ x, unsigned short* __restrict__ xb, int n8) {
    int i = blockIdx.x * 256 + threadIdx.x;
    const int stride = gridDim.x * 256;
    for (; i < n8; i += stride) {
        floatx4 a = *(const floatx4*)(x + (size_t)i * 8);
        floatx4 b = *(const floatx4*)(x + (size_t)i * 8 + 4);
        union { short8 v; uint32_t u[4]; } o;
        o.u[0] = pkh(a[0], a[1]);
        o.u[1] = pkh(a[2], a[3]);
        o.u[2] = pkh(b[0], b[1]);
        o.u[3] = pkh(b[2], b[3]);
        *(short8*)(xb + (size_t)i * 8) = o.v;
    }
}

// ---- pass 0b: dequantize W into per-(256-col-tile, K-step) images ----
// region (nt, t): 16 KB = [kb=4][col=256][k8=8] f16; k = t*32+kb*8+k8, n = nt*256+col.
__global__ __launch_bounds__(512)
void deq_w2(const int* __restrict__ qweight, const int* __restrict__ qzeros,
            const float* __restrict__ scales, unsigned short* __restrict__ wb) {
    const int nt = blockIdx.x;          // 0..42
    const int t  = blockIdx.y;          // 0..127
    const int c  = threadIdx.x & 255;   // local col
    const int kh = threadIdx.x >> 8;    // 0/1 -> kb pair
    const int g  = t >> 2;
    const int col  = nt * 256 + c;
    const int sh   = ((c & 1) ? 16 : 0) + ((c & 7) >> 1) * 4;   // AWQ inverse order
    const int word = nt * 32 + (c >> 3);

    const uint32_t zw = (uint32_t)qzeros[(size_t)g * NQ_DIM + word];
    const uint32_t zn = ((zw >> sh) & 0xFu) | 0x6400u;          // 1024 + z
    const half2v zt = u2h(zn | (zn << 16));
    const float s = scales[(size_t)g * N_DIM + col];
    half2v st; st[0] = (_Float16)s; st[1] = (_Float16)s;

    const int* qp = qweight + (size_t)(t * 32 + kh * 16) * NQ_DIM + word;
    unsigned short* wt = wb + ((size_t)nt * NSTEPS + t) * 8192;

#pragma unroll
    for (int h = 0; h < 2; ++h) {                               // kb = kh*2 + h
        union { half8 v; uint32_t u[4]; } o;
#pragma unroll
        for (int p = 0; p < 4; ++p) {
            const uint32_t qa = (uint32_t)qp[(size_t)(h * 8 + 2 * p)     * NQ_DIM];
            const uint32_t qb = (uint32_t)qp[(size_t)(h * 8 + 2 * p + 1) * NQ_DIM];
            uint32_t u = ((qa >> sh) & 0xFu) | (((qb >> sh) & 0xFu) << 16) | 0x64006400u;
            o.u[p] = h2u((u2h(u) - zt) * st);                   // exact int sub, fp16 mul
        }
        *(half8*)(wt + (size_t)((kh * 2 + h) * 2048 + c * 8)) = o.v;
    }
}

// ---- main GEMM: 256x256 tile, 512 thr (8 waves 2Mx4N), depth-3 phase pipeline ----
// LDS buf d (d=0..2) at d*32768: A [kb=4][row=256][8k] 16KB ; B [kb=4][col=256][8k] 16KB.
// Per K-step: vmcnt(8) + barrier (tile t ready; t+1,t+2 in flight) -> 4 phases of
// {2 A-frag reads, setprio(1) 8 MFMA setprio(0), sched_barrier} -> barrier -> stage t+3.
__global__ __launch_bounds__(512, 2)
void awq_gemm9(const unsigned short* __restrict__ xb,
               const unsigned short* __restrict__ wb,
               const float* __restrict__ bias,
               float* __restrict__ out)
{
    __shared__ char lds[98304] __attribute__((aligned(128)));

    const int tid  = threadIdx.x;
    const int lane = tid & 63;
    const int wid  = tid >> 6;          // 0..7
    const int wr   = wid >> 2;          // M half (0..1)
    const int wc   = wid & 3;           // N quarter (0..3)

    // super-tile swizzle: m-fastest within super-rows of 8 m-tiles (M/256 = 32 = 4*8)
    const int flat = blockIdx.y * NT2 + blockIdx.x;
    const int per_super = NT2 * SUPER2;
    const int s  = flat / per_super;
    const int r  = flat % per_super;
    const int nt = r >> 3;
    const int mt = (s << 3) + (r & 7);
    const int n0 = nt * 256;
    const int m0 = mt * 256;

    // staging: per wave 2 segments (ids wid*2, wid*2+1); seg s: kb = s&3, blk64 = s>>2
    const int sa0 = wid * 2, sa1 = wid * 2 + 1;
    const int seg_l0 = (sa0 & 3) * 4096 + (sa0 >> 2) * 1024;   // LDS byte off (A region)
    const int seg_l1 = (sa1 & 3) * 4096 + (sa1 >> 2) * 1024;
    const unsigned short* a_g0 = xb + (size_t)(m0 + (sa0 >> 2) * 64 + lane) * K_DIM + (sa0 & 3) * 8;
    const unsigned short* a_g1 = xb + (size_t)(m0 + (sa1 >> 2) * 64 + lane) * K_DIM + (sa1 & 3) * 8;
    const unsigned short* wbase = wb + (size_t)nt * NSTEPS * 8192;
    const int b_go0 = (sa0 & 3) * 2048 + ((sa0 >> 2) * 64 + lane) * 8;   // halfs in tile image
    const int b_go1 = (sa1 & 3) * 2048 + ((sa1 >> 2) * 64 + lane) * 8;

    // fragment offsets (within a buffer)
    const int lm = lane & 15;
    const int kb_l = lane >> 4;
    const int aoff = kb_l * 4096 + (wr * 128 + lm) * 16;       // + i*256
    const int boff = kb_l * 4096 + (wc * 64 + lm) * 16;        // + j*256 (B region at +16384)

    floatx4 acc[8][4];
#pragma unroll
    for (int i = 0; i < 8; ++i)
#pragma unroll
        for (int j = 0; j < 4; ++j)
            acc[i][j] = (floatx4){0.f, 0.f, 0.f, 0.f};

    auto stage = [&](int d, int t) {
        char* base = &lds[d * 32768];
        const unsigned short* bt = wbase + (size_t)t * 8192;
        __builtin_amdgcn_global_load_lds(
            (const __attribute__((address_space(1))) void*)(a_g0 + t * BK),
            (__attribute__((address_space(3))) void*)(base + seg_l0), 16, 0, 0);
        __builtin_amdgcn_global_load_lds(
            (const __attribute__((address_space(1))) void*)(a_g1 + t * BK),
            (__attribute__((address_space(3))) void*)(base + seg_l1), 16, 0, 0);
        __builtin_amdgcn_global_load_lds(
            (const __attribute__((address_space(1))) void*)(bt + b_go0),
            (__attribute__((address_space(3))) void*)(base + 16384 + seg_l0), 16, 0, 0);
        __builtin_amdgcn_global_load_lds(
            (const __attribute__((address_space(1))) void*)(bt + b_go1),
            (__attribute__((address_space(3))) void*)(base + 16384 + seg_l1), 16, 0, 0);
    };
    auto compute = [&](int d) {
        const char* ab = &lds[d * 32768];
        const char* bb = ab + 16384;
        half8 bf[4];
#pragma unroll
        for (int j = 0; j < 4; ++j)
            bf[j] = *(const half8*)(bb + boff + j * 256);
#pragma unroll
        for (int p = 0; p < 4; ++p) {
            half8 a0 = *(const half8*)(ab + aoff + (2 * p) * 256);
            half8 a1 = *(const half8*)(ab + aoff + (2 * p + 1) * 256);
            __builtin_amdgcn_s_setprio(1);
#pragma unroll
            for (int j = 0; j < 4; ++j) {
                acc[2 * p][j]     = __builtin_amdgcn_mfma_f32_16x16x32_f16(a0, bf[j], acc[2 * p][j], 0, 0, 0);
                acc[2 * p + 1][j] = __builtin_amdgcn_mfma_f32_16x16x32_f16(a1, bf[j], acc[2 * p + 1][j], 0, 0, 0);
            }
            __builtin_amdgcn_s_setprio(0);
            __builtin_amdgcn_sched_barrier(0);
        }
    };
    auto step = [&](int d, int tstage) {
        asm volatile("s_waitcnt vmcnt(8)" ::: "memory");   // own tile-t loads done; 8 in flight
        __builtin_amdgcn_s_barrier();
        asm volatile("" ::: "memory");
        __builtin_amdgcn_sched_barrier(0);
        compute(d);
        __builtin_amdgcn_s_barrier();                      // all reads of buf d retired
        stage(d, tstage);                                  // tile t+3 (clamped) -> buf d
    };

    // prologue: fill 3 buffers (12 gl_lds in flight per wave... 4 per wave x 3)
    stage(0, 0);
    stage(1, 1);
    stage(2, 2);

    // main: t = 0..125, uniform vmcnt(8); stage src clamped to 127 (dummy re-stage is
    // harmless: targets a buffer dead for the remaining steps)
    for (int tt = 0; tt < 42; ++tt) {
        const int t = tt * 3;
        int t3 = t + 3; if (t3 > 127) t3 = 127;
        int t4 = t + 4; if (t4 > 127) t4 = 127;
        int t5 = t + 5; if (t5 > 127) t5 = 127;
        step(0, t3);
        step(1, t4);
        step(2, t5);
    }
    // t = 126 (buf 0): outstanding = t126, t127, dummy -> vmcnt(8) waits t126
    asm volatile("s_waitcnt vmcnt(8)" ::: "memory");
    __builtin_amdgcn_s_barrier();
    asm volatile("" ::: "memory");
    compute(0);
    // t = 127 (buf 1): outstanding = t127, dummy -> vmcnt(4) waits t127
    asm volatile("s_waitcnt vmcnt(4)" ::: "memory");
    __builtin_amdgcn_s_barrier();
    asm volatile("" ::: "memory");
    compute(1);

    // epilogue: C/D col = lane&15, row = (lane>>4)*4 + r ; non-temporal stores
    const int colb = n0 + wc * 64 + lm;
    const int rowb = m0 + wr * 128 + (kb_l << 2);
#pragma unroll
    for (int j = 0; j < 4; ++j) {
        const int col = colb + j * 16;
        const float bias_f = bias[col];
#pragma unroll
        for (int i = 0; i < 8; ++i) {
            const int row = rowb + i * 16;
#pragma unroll
            for (int r4 = 0; r4 < 4; ++r4) {
                __builtin_nontemporal_store(acc[i][j][r4] + bias_f,
                                            &out[(size_t)(row + r4) * N_DIM + col]);
            }
        }
    }
    // drain in-flight dummy gl_lds before block teardown
    asm volatile("s_waitcnt vmcnt(0) lgkmcnt(0)" ::: "memory");
}

// ================= R8 fused kernel (fallback when ws too small) =================
template <bool PRECVT>
__global__ __launch_bounds__(256, 3)
void awq_gemm5(const float* __restrict__ xf,
               const unsigned short* __restrict__ xb,
               const int* __restrict__ qweight,
               const int* __restrict__ qzeros,
               const float* __restrict__ scales,
               const float* __restrict__ bias,
               float* __restrict__ out)
{
    __shared__ char lds[32768] __attribute__((aligned(128)));
    const int tid  = threadIdx.x;
    const int lane = tid & 63;
    const int wid  = tid >> 6;
    const int n0 = blockIdx.x * BN;
    const int m0 = blockIdx.y * BM;

    const unsigned short* agl0 = xb + (size_t)(m0 + lane) * K_DIM + wid * 8;
    const unsigned short* agl1 = xb + (size_t)(m0 + 64 + lane) * K_DIM + wid * 8;
    const float* aptr = xf + (size_t)(m0 + (tid >> 1)) * K_DIM + (tid & 1) * 16;
    const int awr = ((tid & 1) * 2) * 2048 + (tid >> 1) * 16;

    const int nq      = tid & 15;
    const int k_local = (tid >> 4) * 2;
    const int kb_w    = k_local >> 3;
    const int k8      = k_local & 7;
    const int nq7     = nq & 7;
    const int* qp0 = qweight + blockIdx.x * 16 + nq + (size_t)k_local * NQ_DIM;
    const int* qp1 = qp0 + NQ_DIM;
    const int* zp  = qzeros + blockIdx.x * 16 + nq;
    const float* sp = scales + n0 + nq * 8;
    int baddr[8];
#pragma unroll
    for (int j = 0; j < 8; ++j)
        baddr[j] = 16384 + (kb_w * 128 + nq * 8 + (j ^ nq7)) * 16 + k8 * 2;

    const int wm = (wid >> 1) * 64;
    const int wn = (wid & 1) * 64;
    const int lm = lane & 15;
    const int kb_l = lane >> 4;
    const int aoff = kb_l * 2048 + (wm + lm) * 16;
    int boff[4];
#pragma unroll
    for (int j = 0; j < 4; ++j) {
        int blk = kb_l * 128 + wn + j * 16 + lm;
        blk ^= (blk >> 3) & 7;
        boff[j] = 16384 + blk * 16;
    }

    floatx4 acc[4][4];
#pragma unroll
    for (int i = 0; i < 4; ++i)
#pragma unroll
        for (int j = 0; j < 4; ++j)
            acc[i][j] = (floatx4){0.f, 0.f, 0.f, 0.f};

    half2v zt[4], st[4];
    uint32_t q0, q1;

    auto stage_a = [&](int abase) {
        if constexpr (PRECVT) {
            __builtin_amdgcn_global_load_lds(
                (const __attribute__((address_space(1))) void*)agl0,
                (__attribute__((address_space(3))) void*)(&lds[abase + wid * 2048]), 16, 0, 0);
            __builtin_amdgcn_global_load_lds(
                (const __attribute__((address_space(1))) void*)agl1,
                (__attribute__((address_space(3))) void*)(&lds[abase + wid * 2048 + 1024]), 16, 0, 0);
            agl0 += BK; agl1 += BK;
        } else {
            floatx4 a0 = *(const floatx4*)(aptr + 0);
            floatx4 a1 = *(const floatx4*)(aptr + 4);
            floatx4 a2 = *(const floatx4*)(aptr + 8);
            floatx4 a3 = *(const floatx4*)(aptr + 12);
            aptr += BK;
            union { short8 v; uint32_t u[4]; } o0, o1;
            o0.u[0] = pkh(a0[0], a0[1]); o0.u[1] = pkh(a0[2], a0[3]);
            o0.u[2] = pkh(a1[0], a1[1]); o0.u[3] = pkh(a1[2], a1[3]);
            o1.u[0] = pkh(a2[0], a2[1]); o1.u[1] = pkh(a2[2], a2[3]);
            o1.u[2] = pkh(a3[0], a3[1]); o1.u[3] = pkh(a3[2], a3[3]);
            *(short8*)&lds[abase + awr]        = o0.v;
            *(short8*)&lds[abase + awr + 2048] = o1.v;
        }
    };
    auto load_q = [&]() {
        q0 = (uint32_t)*qp0; q1 = (uint32_t)*qp1;
        qp0 += (size_t)BK * NQ_DIM; qp1 += (size_t)BK * NQ_DIM;
    };
    auto refresh = [&]() {
        const uint32_t zw = (uint32_t)*zp;
        zp += NQ_DIM;
#pragma unroll
        for (int l = 0; l < 4; ++l) {
            zt[l] = u2h(((zw >> (4 * l)) & 0x000F000Fu) | 0x64006400u);
            float2v s2 = *(const float2v*)(sp + 2 * l);
            half2v sh2; sh2[0] = (_Float16)s2[0]; sh2[1] = (_Float16)s2[1];
            st[l] = sh2;
        }
        sp += N_DIM;
    };
    auto deq_store = [&](int off) {
#pragma unroll
        for (int l = 0; l < 4; ++l) {
            uint32_t t0 = ((q0 >> (4 * l)) & 0x000F000Fu) | 0x64006400u;
            uint32_t t1 = ((q1 >> (4 * l)) & 0x000F000Fu) | 0x64006400u;
            half2v w0 = (u2h(t0) - zt[l]) * st[l];
            half2v w1 = (u2h(t1) - zt[l]) * st[l];
            uint32_t p0 = h2u(w0), p1 = h2u(w1);
            uint32_t de = (p0 & 0xFFFFu) | (p1 << 16);
            uint32_t dd = (p0 >> 16) | (p1 & 0xFFFF0000u);
            *(uint32_t*)&lds[baddr[2 * l]     + off] = de;
            *(uint32_t*)&lds[baddr[2 * l + 1] + off] = dd;
        }
    };
    auto compute = [&](int ab, int bb) {
        half8 af[4], bfr[4];
#pragma unroll
        for (int i = 0; i < 4; ++i) af[i] = *(const half8*)&lds[ab + aoff + i * 256];
#pragma unroll
        for (int j = 0; j < 4; ++j) bfr[j] = *(const half8*)&lds[bb + boff[j] - 16384];
#pragma unroll
        for (int i = 0; i < 4; ++i)
#pragma unroll
            for (int j = 0; j < 4; ++j)
                acc[i][j] = __builtin_amdgcn_mfma_f32_16x16x32_f16(af[i], bfr[j], acc[i][j], 0, 0, 0);
    };

    stage_a(0); load_q(); refresh(); deq_store(0); load_q();
    __syncthreads();

    for (int t = 0; t < NSTEPS; t += 2) {
        stage_a(8192);
        deq_store(8192);
        if (t + 2 < NSTEPS) load_q();
        compute(0, 16384);
        __syncthreads();
        if (t + 2 < NSTEPS) {
            stage_a(0);
            if (((t + 2) & 3) == 0) refresh();
            deq_store(0);
            if (t + 3 < NSTEPS) load_q();
        }
        compute(8192, 24576);
        __syncthreads();
    }

    const int colb = n0 + wn + lm;
    const int rowb = m0 + wm + (kb_l << 2);
#pragma unroll
    for (int j = 0; j < 4; ++j) {
        const int col = colb + j * 16;
        const float bias_f = bias[col];
#pragma unroll
        for (int i = 0; i < 4; ++i) {
            const int row = rowb + i * 16;
#pragma unroll
            for (int r4 = 0; r4 < 4; ++r4) {
                out[(size_t)(row + r4) * N_DIM + col] = acc[i][j][r4] + bias_f;
            }
        }
    }
}

extern "C" void kernel_launch(void* const* d_in, const int* in_sizes, int n_in,
                              void* d_out, int out_size, void* d_ws, size_t ws_size,
                              hipStream_t stream) {
    const float* x    = (const float*)d_in[0];
    const int* qw     = (const int*)d_in[1];
    const int* qz     = (const int*)d_in[2];
    const float* sc   = (const float*)d_in[3];
    const float* bi   = (const float*)d_in[4];
    float* out        = (float*)d_out;

    const int M = in_sizes[0] / K_DIM;                       // 8192
    const size_t xb_bytes = (size_t)M * K_DIM * 2;           // 64 MiB
    const size_t wb_bytes = (size_t)K_DIM * N_DIM * 2;       // 86 MiB

    if (ws_size >= xb_bytes + wb_bytes) {
        unsigned short* xb = (unsigned short*)d_ws;
        unsigned short* wb = (unsigned short*)((char*)d_ws + xb_bytes);
        const int n8 = (int)((size_t)M * K_DIM / 8);
        cvt_x<<<2048, 256, 0, stream>>>(x, xb, n8);
        deq_w2<<<dim3(NT2, NSTEPS), 512, 0, stream>>>(qw, qz, sc, wb);
        awq_gemm9<<<dim3(NT2, M / 256), 512, 0, stream>>>(xb, wb, bi, out);
    } else if (ws_size >= xb_bytes) {
        unsigned short* xb = (unsigned short*)d_ws;
        const int n8 = (int)((size_t)M * K_DIM / 8);
        cvt_x<<<2048, 256, 0, stream>>>(x, xb, n8);
        awq_gemm5<true><<<dim3(NT_DIM, M / BM), 256, 0, stream>>>(x, xb, qw, qz, sc, bi, out);
    } else {
        awq_gemm5<false><<<dim3(NT_DIM, M / BM), 256, 0, stream>>>(x, nullptr, qw, qz, sc, bi, out);
    }
}

// Round 14
// 938.355 us; speedup vs baseline: 1.4580x; 1.0024x over previous
//
#include <hip/hip_runtime.h>
#include <hip/hip_fp16.h>
#include <stdint.h>

typedef __attribute__((ext_vector_type(8))) _Float16 half8;
typedef __attribute__((ext_vector_type(2))) _Float16 half2v;
typedef __attribute__((ext_vector_type(8))) short short8;
typedef __attribute__((ext_vector_type(4))) float floatx4;
typedef __attribute__((ext_vector_type(2))) float float2v;

#define K_DIM 4096
#define N_DIM 11008
#define NQ_DIM 1376
#define NSTEPS 128
#define BK 32
// 256x256 kernel geometry
#define NT2 43
// fallback 128x128 geometry
#define BM 128
#define BN 128
#define NT_DIM 86

__device__ __forceinline__ uint32_t pkh(float a, float b) {
    half2v h; h[0] = (_Float16)a; h[1] = (_Float16)b;
    union { half2v h; uint32_t u; } c; c.h = h; return c.u;
}
__device__ __forceinline__ half2v u2h(uint32_t u) {
    union { uint32_t u; half2v h; } c; c.u = u; return c.h;
}
__device__ __forceinline__ uint32_t h2u(half2v h) {
    union { half2v h; uint32_t u; } c; c.h = h; return c.u;
}

// ---- pass 0a: x f32 -> f16 ----
__global__ __launch_bounds__(256)
void cvt_x(const float* __restrict__ x, unsigned short* __restrict__ xb, int n8) {
    int i = blockIdx.x * 256 + threadIdx.x;
    const int stride = gridDim.x * 256;
    for (; i < n8; i += stride) {
        floatx4 a = *(const floatx4*)(x + (size_t)i * 8);
        floatx4 b = *(const floatx4*)(x + (size_t)i * 8 + 4);
        union { short8 v; uint32_t u[4]; } o;
        o.u[0] = pkh(a[0], a[1]);
        o.u[1] = pkh(a[2], a[3]);
        o.u[2] = pkh(b[0], b[1]);
        o.u[3] = pkh(b[2], b[3]);
        *(short8*)(xb + (size_t)i * 8) = o.v;
    }
}

// ---- pass 0b: dequantize W into per-(256-col-tile, K-step) images ----
// region (nt, t): 16 KB = [kb=4][col=256][k8=8] f16; k = t*32+kb*8+k8, n = nt*256+col.
__global__ __launch_bounds__(512)
void deq_w2(const int* __restrict__ qweight, const int* __restrict__ qzeros,
            const float* __restrict__ scales, unsigned short* __restrict__ wb) {
    const int nt = blockIdx.x;          // 0..42
    const int t  = blockIdx.y;          // 0..127
    const int c  = threadIdx.x & 255;   // local col
    const int kh = threadIdx.x >> 8;    // 0/1 -> kb pair
    const int g  = t >> 2;
    const int col  = nt * 256 + c;
    const int sh   = ((c & 1) ? 16 : 0) + ((c & 7) >> 1) * 4;   // AWQ inverse order
    const int word = nt * 32 + (c >> 3);

    const uint32_t zw = (uint32_t)qzeros[(size_t)g * NQ_DIM + word];
    const uint32_t zn = ((zw >> sh) & 0xFu) | 0x6400u;          // 1024 + z
    const half2v zt = u2h(zn | (zn << 16));
    const float s = scales[(size_t)g * N_DIM + col];
    half2v st; st[0] = (_Float16)s; st[1] = (_Float16)s;

    const int* qp = qweight + (size_t)(t * 32 + kh * 16) * NQ_DIM + word;
    unsigned short* wt = wb + ((size_t)nt * NSTEPS + t) * 8192;

#pragma unroll
    for (int h = 0; h < 2; ++h) {                               // kb = kh*2 + h
        union { half8 v; uint32_t u[4]; } o;
#pragma unroll
        for (int p = 0; p < 4; ++p) {
            const uint32_t qa = (uint32_t)qp[(size_t)(h * 8 + 2 * p)     * NQ_DIM];
            const uint32_t qb = (uint32_t)qp[(size_t)(h * 8 + 2 * p + 1) * NQ_DIM];
            uint32_t u = ((qa >> sh) & 0xFu) | (((qb >> sh) & 0xFu) << 16) | 0x64006400u;
            o.u[p] = h2u((u2h(u) - zt) * st);                   // exact int sub, fp16 mul
        }
        *(half8*)(wt + (size_t)((kh * 2 + h) * 2048 + c * 8)) = o.v;
    }
}

// ---- main GEMM: 256x256 tile, 512 thr (8 waves 2Mx4N), depth-3 phase pipeline ----
// LDS buf d (d=0..2) at d*32768: A [kb=4][row=256][8k] 16KB ; B [kb=4][col=256][8k] 16KB.
// 2-D launch window: 3 nt-groups (16/16/11 wide), nt fastest inside a group ->
// any 256 consecutive block ids cover a 16mt x 16nt patch (32MB xb + 32MB wb, L3-fit).
__global__ __launch_bounds__(512, 2)
void awq_gemm9(const unsigned short* __restrict__ xb,
               const unsigned short* __restrict__ wb,
               const float* __restrict__ bias,
               float* __restrict__ out)
{
    __shared__ char lds[98304] __attribute__((aligned(128)));

    const int tid  = threadIdx.x;
    const int lane = tid & 63;
    const int wid  = tid >> 6;          // 0..7
    const int wr   = wid >> 2;          // M half (0..1)
    const int wc   = wid & 3;           // N quarter (0..3)

    // ---- 2-D window swizzle ----
    const int flat = blockIdx.y * NT2 + blockIdx.x;   // 0..1375
    int nt, mt;
    if (flat < 1024) {                 // groups 0,1 (nt width 16)
        const int g = flat >> 9;       // 0 or 1
        const int r = flat & 511;
        nt = g * 16 + (r & 15);
        mt = r >> 4;
    } else {                           // group 2 (nt width 11)
        const int r = flat - 1024;
        mt = r / 11;
        nt = 32 + (r - mt * 11);
    }
    const int n0 = nt * 256;
    const int m0 = mt * 256;

    // staging: per wave 2 segments (ids wid*2, wid*2+1); seg s: kb = s&3, blk64 = s>>2
    const int sa0 = wid * 2, sa1 = wid * 2 + 1;
    const int seg_l0 = (sa0 & 3) * 4096 + (sa0 >> 2) * 1024;   // LDS byte off (A region)
    const int seg_l1 = (sa1 & 3) * 4096 + (sa1 >> 2) * 1024;
    const unsigned short* a_g0 = xb + (size_t)(m0 + (sa0 >> 2) * 64 + lane) * K_DIM + (sa0 & 3) * 8;
    const unsigned short* a_g1 = xb + (size_t)(m0 + (sa1 >> 2) * 64 + lane) * K_DIM + (sa1 & 3) * 8;
    const unsigned short* wbase = wb + (size_t)nt * NSTEPS * 8192;
    const int b_go0 = (sa0 & 3) * 2048 + ((sa0 >> 2) * 64 + lane) * 8;   // halfs in tile image
    const int b_go1 = (sa1 & 3) * 2048 + ((sa1 >> 2) * 64 + lane) * 8;

    // fragment offsets (within a buffer)
    const int lm = lane & 15;
    const int kb_l = lane >> 4;
    const int aoff = kb_l * 4096 + (wr * 128 + lm) * 16;       // + i*256
    const int boff = kb_l * 4096 + (wc * 64 + lm) * 16;        // + j*256 (B region at +16384)

    floatx4 acc[8][4];
#pragma unroll
    for (int i = 0; i < 8; ++i)
#pragma unroll
        for (int j = 0; j < 4; ++j)
            acc[i][j] = (floatx4){0.f, 0.f, 0.f, 0.f};

    auto stage = [&](int d, int t) {
        char* base = &lds[d * 32768];
        const unsigned short* bt = wbase + (size_t)t * 8192;
        __builtin_amdgcn_global_load_lds(
            (const __attribute__((address_space(1))) void*)(a_g0 + t * BK),
            (__attribute__((address_space(3))) void*)(base + seg_l0), 16, 0, 0);
        __builtin_amdgcn_global_load_lds(
            (const __attribute__((address_space(1))) void*)(a_g1 + t * BK),
            (__attribute__((address_space(3))) void*)(base + seg_l1), 16, 0, 0);
        __builtin_amdgcn_global_load_lds(
            (const __attribute__((address_space(1))) void*)(bt + b_go0),
            (__attribute__((address_space(3))) void*)(base + 16384 + seg_l0), 16, 0, 0);
        __builtin_amdgcn_global_load_lds(
            (const __attribute__((address_space(1))) void*)(bt + b_go1),
            (__attribute__((address_space(3))) void*)(base + 16384 + seg_l1), 16, 0, 0);
    };
    auto compute = [&](int d) {
        const char* ab = &lds[d * 32768];
        const char* bb = ab + 16384;
        half8 bf[4];
#pragma unroll
        for (int j = 0; j < 4; ++j)
            bf[j] = *(const half8*)(bb + boff + j * 256);
#pragma unroll
        for (int p = 0; p < 4; ++p) {
            half8 a0 = *(const half8*)(ab + aoff + (2 * p) * 256);
            half8 a1 = *(const half8*)(ab + aoff + (2 * p + 1) * 256);
            __builtin_amdgcn_s_setprio(1);
#pragma unroll
            for (int j = 0; j < 4; ++j) {
                acc[2 * p][j]     = __builtin_amdgcn_mfma_f32_16x16x32_f16(a0, bf[j], acc[2 * p][j], 0, 0, 0);
                acc[2 * p + 1][j] = __builtin_amdgcn_mfma_f32_16x16x32_f16(a1, bf[j], acc[2 * p + 1][j], 0, 0, 0);
            }
            __builtin_amdgcn_s_setprio(0);
            __builtin_amdgcn_sched_barrier(0);
        }
    };
    auto step = [&](int d, int tstage) {
        asm volatile("s_waitcnt vmcnt(8)" ::: "memory");   // own tile-t loads done; 8 in flight
        __builtin_amdgcn_s_barrier();
        asm volatile("" ::: "memory");
        __builtin_amdgcn_sched_barrier(0);
        compute(d);
        __builtin_amdgcn_s_barrier();                      // all reads of buf d retired
        stage(d, tstage);                                  // tile t+3 (clamped) -> buf d
    };

    // prologue: fill 3 buffers
    stage(0, 0);
    stage(1, 1);
    stage(2, 2);

    for (int tt = 0; tt < 42; ++tt) {
        const int t = tt * 3;
        int t3 = t + 3; if (t3 > 127) t3 = 127;
        int t4 = t + 4; if (t4 > 127) t4 = 127;
        int t5 = t + 5; if (t5 > 127) t5 = 127;
        step(0, t3);
        step(1, t4);
        step(2, t5);
    }
    // t = 126 (buf 0): outstanding = t126, t127, dummy -> vmcnt(8) waits t126
    asm volatile("s_waitcnt vmcnt(8)" ::: "memory");
    __builtin_amdgcn_s_barrier();
    asm volatile("" ::: "memory");
    compute(0);
    // t = 127 (buf 1): outstanding = t127, dummy -> vmcnt(4) waits t127
    asm volatile("s_waitcnt vmcnt(4)" ::: "memory");
    __builtin_amdgcn_s_barrier();
    asm volatile("" ::: "memory");
    compute(1);

    // epilogue: C/D col = lane&15, row = (lane>>4)*4 + r ; non-temporal stores
    const int colb = n0 + wc * 64 + lm;
    const int rowb = m0 + wr * 128 + (kb_l << 2);
#pragma unroll
    for (int j = 0; j < 4; ++j) {
        const int col = colb + j * 16;
        const float bias_f = bias[col];
#pragma unroll
        for (int i = 0; i < 8; ++i) {
            const int row = rowb + i * 16;
#pragma unroll
            for (int r4 = 0; r4 < 4; ++r4) {
                __builtin_nontemporal_store(acc[i][j][r4] + bias_f,
                                            &out[(size_t)(row + r4) * N_DIM + col]);
            }
        }
    }
    // drain in-flight dummy gl_lds before block teardown
    asm volatile("s_waitcnt vmcnt(0) lgkmcnt(0)" ::: "memory");
}

// ================= R8 fused kernel (fallback when ws too small) =================
template <bool PRECVT>
__global__ __launch_bounds__(256, 3)
void awq_gemm5(const float* __restrict__ xf,
               const unsigned short* __restrict__ xb,
               const int* __restrict__ qweight,
               const int* __restrict__ qzeros,
               const float* __restrict__ scales,
               const float* __restrict__ bias,
               float* __restrict__ out)
{
    __shared__ char lds[32768] __attribute__((aligned(128)));
    const int tid  = threadIdx.x;
    const int lane = tid & 63;
    const int wid  = tid >> 6;
    const int n0 = blockIdx.x * BN;
    const int m0 = blockIdx.y * BM;

    const unsigned short* agl0 = xb + (size_t)(m0 + lane) * K_DIM + wid * 8;
    const unsigned short* agl1 = xb + (size_t)(m0 + 64 + lane) * K_DIM + wid * 8;
    const float* aptr = xf + (size_t)(m0 + (tid >> 1)) * K_DIM + (tid & 1) * 16;
    const int awr = ((tid & 1) * 2) * 2048 + (tid >> 1) * 16;

    const int nq      = tid & 15;
    const int k_local = (tid >> 4) * 2;
    const int kb_w    = k_local >> 3;
    const int k8      = k_local & 7;
    const int nq7     = nq & 7;
    const int* qp0 = qweight + blockIdx.x * 16 + nq + (size_t)k_local * NQ_DIM;
    const int* qp1 = qp0 + NQ_DIM;
    const int* zp  = qzeros + blockIdx.x * 16 + nq;
    const float* sp = scales + n0 + nq * 8;
    int baddr[8];
#pragma unroll
    for (int j = 0; j < 8; ++j)
        baddr[j] = 16384 + (kb_w * 128 + nq * 8 + (j ^ nq7)) * 16 + k8 * 2;

    const int wm = (wid >> 1) * 64;
    const int wn = (wid & 1) * 64;
    const int lm = lane & 15;
    const int kb_l = lane >> 4;
    const int aoff = kb_l * 2048 + (wm + lm) * 16;
    int boff[4];
#pragma unroll
    for (int j = 0; j < 4; ++j) {
        int blk = kb_l * 128 + wn + j * 16 + lm;
        blk ^= (blk >> 3) & 7;
        boff[j] = 16384 + blk * 16;
    }

    floatx4 acc[4][4];
#pragma unroll
    for (int i = 0; i < 4; ++i)
#pragma unroll
        for (int j = 0; j < 4; ++j)
            acc[i][j] = (floatx4){0.f, 0.f, 0.f, 0.f};

    half2v zt[4], st[4];
    uint32_t q0, q1;

    auto stage_a = [&](int abase) {
        if constexpr (PRECVT) {
            __builtin_amdgcn_global_load_lds(
                (const __attribute__((address_space(1))) void*)agl0,
                (__attribute__((address_space(3))) void*)(&lds[abase + wid * 2048]), 16, 0, 0);
            __builtin_amdgcn_global_load_lds(
                (const __attribute__((address_space(1))) void*)agl1,
                (__attribute__((address_space(3))) void*)(&lds[abase + wid * 2048 + 1024]), 16, 0, 0);
            agl0 += BK; agl1 += BK;
        } else {
            floatx4 a0 = *(const floatx4*)(aptr + 0);
            floatx4 a1 = *(const floatx4*)(aptr + 4);
            floatx4 a2 = *(const floatx4*)(aptr + 8);
            floatx4 a3 = *(const floatx4*)(aptr + 12);
            aptr += BK;
            union { short8 v; uint32_t u[4]; } o0, o1;
            o0.u[0] = pkh(a0[0], a0[1]); o0.u[1] = pkh(a0[2], a0[3]);
            o0.u[2] = pkh(a1[0], a1[1]); o0.u[3] = pkh(a1[2], a1[3]);
            o1.u[0] = pkh(a2[0], a2[1]); o1.u[1] = pkh(a2[2], a2[3]);
            o1.u[2] = pkh(a3[0], a3[1]); o1.u[3] = pkh(a3[2], a3[3]);
            *(short8*)&lds[abase + awr]        = o0.v;
            *(short8*)&lds[abase + awr + 2048] = o1.v;
        }
    };
    auto load_q = [&]() {
        q0 = (uint32_t)*qp0; q1 = (uint32_t)*qp1;
        qp0 += (size_t)BK * NQ_DIM; qp1 += (size_t)BK * NQ_DIM;
    };
    auto refresh = [&]() {
        const uint32_t zw = (uint32_t)*zp;
        zp += NQ_DIM;
#pragma unroll
        for (int l = 0; l < 4; ++l) {
            zt[l] = u2h(((zw >> (4 * l)) & 0x000F000Fu) | 0x64006400u);
            float2v s2 = *(const float2v*)(sp + 2 * l);
            half2v sh2; sh2[0] = (_Float16)s2[0]; sh2[1] = (_Float16)s2[1];
            st[l] = sh2;
        }
        sp += N_DIM;
    };
    auto deq_store = [&](int off) {
#pragma unroll
        for (int l = 0; l < 4; ++l) {
            uint32_t t0 = ((q0 >> (4 * l)) & 0x000F000Fu) | 0x64006400u;
            uint32_t t1 = ((q1 >> (4 * l)) & 0x000F000Fu) | 0x64006400u;
            half2v w0 = (u2h(t0) - zt[l]) * st[l];
            half2v w1 = (u2h(t1) - zt[l]) * st[l];
            uint32_t p0 = h2u(w0), p1 = h2u(w1);
            uint32_t de = (p0 & 0xFFFFu) | (p1 << 16);
            uint32_t dd = (p0 >> 16) | (p1 & 0xFFFF0000u);
            *(uint32_t*)&lds[baddr[2 * l]     + off] = de;
            *(uint32_t*)&lds[baddr[2 * l + 1] + off] = dd;
        }
    };
    auto compute = [&](int ab, int bb) {
        half8 af[4], bfr[4];
#pragma unroll
        for (int i = 0; i < 4; ++i) af[i] = *(const half8*)&lds[ab + aoff + i * 256];
#pragma unroll
        for (int j = 0; j < 4; ++j) bfr[j] = *(const half8*)&lds[bb + boff[j] - 16384];
#pragma unroll
        for (int i = 0; i < 4; ++i)
#pragma unroll
            for (int j = 0; j < 4; ++j)
                acc[i][j] = __builtin_amdgcn_mfma_f32_16x16x32_f16(af[i], bfr[j], acc[i][j], 0, 0, 0);
    };

    stage_a(0); load_q(); refresh(); deq_store(0); load_q();
    __syncthreads();

    for (int t = 0; t < NSTEPS; t += 2) {
        stage_a(8192);
        deq_store(8192);
        if (t + 2 < NSTEPS) load_q();
        compute(0, 16384);
        __syncthreads();
        if (t + 2 < NSTEPS) {
            stage_a(0);
            if (((t + 2) & 3) == 0) refresh();
            deq_store(0);
            if (t + 3 < NSTEPS) load_q();
        }
        compute(8192, 24576);
        __syncthreads();
    }

    const int colb = n0 + wn + lm;
    const int rowb = m0 + wm + (kb_l << 2);
#pragma unroll
    for (int j = 0; j < 4; ++j) {
        const int col = colb + j * 16;
        const float bias_f = bias[col];
#pragma unroll
        for (int i = 0; i < 4; ++i) {
            const int row = rowb + i * 16;
#pragma unroll
            for (int r4 = 0; r4 < 4; ++r4) {
                out[(size_t)(row + r4) * N_DIM + col] = acc[i][j][r4] + bias_f;
            }
        }
    }
}

extern "C" void kernel_launch(void* const* d_in, const int* in_sizes, int n_in,
                              void* d_out, int out_size, void* d_ws, size_t ws_size,
                              hipStream_t stream) {
    const float* x    = (const float*)d_in[0];
    const int* qw     = (const int*)d_in[1];
    const int* qz     = (const int*)d_in[2];
    const float* sc   = (const float*)d_in[3];
    const float* bi   = (const float*)d_in[4];
    float* out        = (float*)d_out;

    const int M = in_sizes[0] / K_DIM;                       // 8192
    const size_t xb_bytes = (size_t)M * K_DIM * 2;           // 64 MiB
    const size_t wb_bytes = (size_t)K_DIM * N_DIM * 2;       // 86 MiB

    if (ws_size >= xb_bytes + wb_bytes) {
        unsigned short* xb = (unsigned short*)d_ws;
        unsigned short* wb = (unsigned short*)((char*)d_ws + xb_bytes);
        const int n8 = (int)((size_t)M * K_DIM / 8);
        cvt_x<<<2048, 256, 0, stream>>>(x, xb, n8);
        deq_w2<<<dim3(NT2, NSTEPS), 512, 0, stream>>>(qw, qz, sc, wb);
        awq_gemm9<<<dim3(NT2, M / 256), 512, 0, stream>>>(xb, wb, bi, out);
    } else if (ws_size >= xb_bytes) {
        unsigned short* xb = (unsigned short*)d_ws;
        const int n8 = (int)((size_t)M * K_DIM / 8);
        cvt_x<<<2048, 256, 0, stream>>>(x, xb, n8);
        awq_gemm5<true><<<dim3(NT_DIM, M / BM), 256, 0, stream>>>(x, xb, qw, qz, sc, bi, out);
    } else {
        awq_gemm5<false><<<dim3(NT_DIM, M / BM), 256, 0, stream>>>(x, nullptr, qw, qz, sc, bi, out);
    }
}

// Round 15
// 930.482 us; speedup vs baseline: 1.4704x; 1.0085x over previous
//
#include <hip/hip_runtime.h>
#include <hip/hip_fp16.h>
#include <stdint.h>

typedef __attribute__((ext_vector_type(8))) _Float16 half8;
typedef __attribute__((ext_vector_type(2))) _Float16 half2v;
typedef __attribute__((ext_vector_type(8))) short short8;
typedef __attribute__((ext_vector_type(4))) float floatx4;
typedef __attribute__((ext_vector_type(2))) float float2v;

#define K_DIM 4096
#define N_DIM 11008
#define NQ_DIM 1376
#define NSTEPS 128
#define BK 32
// 256x256 kernel geometry
#define NT2 43
// fallback 128x128 geometry
#define BM 128
#define BN 128
#define NT_DIM 86

__device__ __forceinline__ uint32_t pkh(float a, float b) {
    half2v h; h[0] = (_Float16)a; h[1] = (_Float16)b;
    union { half2v h; uint32_t u; } c; c.h = h; return c.u;
}
__device__ __forceinline__ half2v u2h(uint32_t u) {
    union { uint32_t u; half2v h; } c; c.u = u; return c.h;
}
__device__ __forceinline__ uint32_t h2u(half2v h) {
    union { half2v h; uint32_t u; } c; c.h = h; return c.u;
}

// ---- pass 0a: x f32 -> f16 ----
__global__ __launch_bounds__(256)
void cvt_x(const float* __restrict__ x, unsigned short* __restrict__ xb, int n8) {
    int i = blockIdx.x * 256 + threadIdx.x;
    const int stride = gridDim.x * 256;
    for (; i < n8; i += stride) {
        floatx4 a = *(const floatx4*)(x + (size_t)i * 8);
        floatx4 b = *(const floatx4*)(x + (size_t)i * 8 + 4);
        union { short8 v; uint32_t u[4]; } o;
        o.u[0] = pkh(a[0], a[1]);
        o.u[1] = pkh(a[2], a[3]);
        o.u[2] = pkh(b[0], b[1]);
        o.u[3] = pkh(b[2], b[3]);
        *(short8*)(xb + (size_t)i * 8) = o.v;
    }
}

// ---- pass 0b: dequantize W into per-(256-col-tile, K-step) images ----
// region (nt, t): 16 KB = [kb=4][col=256][k8=8] f16; k = t*32+kb*8+k8, n = nt*256+col.
__global__ __launch_bounds__(512)
void deq_w2(const int* __restrict__ qweight, const int* __restrict__ qzeros,
            const float* __restrict__ scales, unsigned short* __restrict__ wb) {
    const int nt = blockIdx.x;          // 0..42
    const int t  = blockIdx.y;          // 0..127
    const int c  = threadIdx.x & 255;   // local col
    const int kh = threadIdx.x >> 8;    // 0/1 -> kb pair
    const int g  = t >> 2;
    const int col  = nt * 256 + c;
    const int sh   = ((c & 1) ? 16 : 0) + ((c & 7) >> 1) * 4;   // AWQ inverse order
    const int word = nt * 32 + (c >> 3);

    const uint32_t zw = (uint32_t)qzeros[(size_t)g * NQ_DIM + word];
    const uint32_t zn = ((zw >> sh) & 0xFu) | 0x6400u;          // 1024 + z
    const half2v zt = u2h(zn | (zn << 16));
    const float s = scales[(size_t)g * N_DIM + col];
    half2v st; st[0] = (_Float16)s; st[1] = (_Float16)s;

    const int* qp = qweight + (size_t)(t * 32 + kh * 16) * NQ_DIM + word;
    unsigned short* wt = wb + ((size_t)nt * NSTEPS + t) * 8192;

#pragma unroll
    for (int h = 0; h < 2; ++h) {                               // kb = kh*2 + h
        union { half8 v; uint32_t u[4]; } o;
#pragma unroll
        for (int p = 0; p < 4; ++p) {
            const uint32_t qa = (uint32_t)qp[(size_t)(h * 8 + 2 * p)     * NQ_DIM];
            const uint32_t qb = (uint32_t)qp[(size_t)(h * 8 + 2 * p + 1) * NQ_DIM];
            uint32_t u = ((qa >> sh) & 0xFu) | (((qb >> sh) & 0xFu) << 16) | 0x64006400u;
            o.u[p] = h2u((u2h(u) - zt) * st);                   // exact int sub, fp16 mul
        }
        *(half8*)(wt + (size_t)((kh * 2 + h) * 2048 + c * 8)) = o.v;
    }
}

// ---- main GEMM: 256x256 tile, 512 thr (8 waves 2Mx4N), depth-3 phase pipeline ----
// LDS buf d (d=0..2) at d*32768: A [kb=4][row=256][8k] 16KB ; B [kb=4][col=256][8k] 16KB.
// R15: NO sched_barrier pinning inside compute -- the compiler is free to hoist
// next-phase ds_reads under current-phase MFMAs (bounded by launch_bounds reg cap).
__global__ __launch_bounds__(512, 2)
void awq_gemm9(const unsigned short* __restrict__ xb,
               const unsigned short* __restrict__ wb,
               const float* __restrict__ bias,
               float* __restrict__ out)
{
    __shared__ char lds[98304] __attribute__((aligned(128)));

    const int tid  = threadIdx.x;
    const int lane = tid & 63;
    const int wid  = tid >> 6;          // 0..7
    const int wr   = wid >> 2;          // M half (0..1)
    const int wc   = wid & 3;           // N quarter (0..3)

    // ---- 2-D window swizzle ----
    const int flat = blockIdx.y * NT2 + blockIdx.x;   // 0..1375
    int nt, mt;
    if (flat < 1024) {                 // groups 0,1 (nt width 16)
        const int g = flat >> 9;       // 0 or 1
        const int r = flat & 511;
        nt = g * 16 + (r & 15);
        mt = r >> 4;
    } else {                           // group 2 (nt width 11)
        const int r = flat - 1024;
        mt = r / 11;
        nt = 32 + (r - mt * 11);
    }
    const int n0 = nt * 256;
    const int m0 = mt * 256;

    // staging: per wave 2 segments (ids wid*2, wid*2+1); seg s: kb = s&3, blk64 = s>>2
    const int sa0 = wid * 2, sa1 = wid * 2 + 1;
    const int seg_l0 = (sa0 & 3) * 4096 + (sa0 >> 2) * 1024;   // LDS byte off (A region)
    const int seg_l1 = (sa1 & 3) * 4096 + (sa1 >> 2) * 1024;
    const unsigned short* a_g0 = xb + (size_t)(m0 + (sa0 >> 2) * 64 + lane) * K_DIM + (sa0 & 3) * 8;
    const unsigned short* a_g1 = xb + (size_t)(m0 + (sa1 >> 2) * 64 + lane) * K_DIM + (sa1 & 3) * 8;
    const unsigned short* wbase = wb + (size_t)nt * NSTEPS * 8192;
    const int b_go0 = (sa0 & 3) * 2048 + ((sa0 >> 2) * 64 + lane) * 8;   // halfs in tile image
    const int b_go1 = (sa1 & 3) * 2048 + ((sa1 >> 2) * 64 + lane) * 8;

    // fragment offsets (within a buffer)
    const int lm = lane & 15;
    const int kb_l = lane >> 4;
    const int aoff = kb_l * 4096 + (wr * 128 + lm) * 16;       // + i*256
    const int boff = kb_l * 4096 + (wc * 64 + lm) * 16;        // + j*256 (B region at +16384)

    floatx4 acc[8][4];
#pragma unroll
    for (int i = 0; i < 8; ++i)
#pragma unroll
        for (int j = 0; j < 4; ++j)
            acc[i][j] = (floatx4){0.f, 0.f, 0.f, 0.f};

    auto stage = [&](int d, int t) {
        char* base = &lds[d * 32768];
        const unsigned short* bt = wbase + (size_t)t * 8192;
        __builtin_amdgcn_global_load_lds(
            (const __attribute__((address_space(1))) void*)(a_g0 + t * BK),
            (__attribute__((address_space(3))) void*)(base + seg_l0), 16, 0, 0);
        __builtin_amdgcn_global_load_lds(
            (const __attribute__((address_space(1))) void*)(a_g1 + t * BK),
            (__attribute__((address_space(3))) void*)(base + seg_l1), 16, 0, 0);
        __builtin_amdgcn_global_load_lds(
            (const __attribute__((address_space(1))) void*)(bt + b_go0),
            (__attribute__((address_space(3))) void*)(base + 16384 + seg_l0), 16, 0, 0);
        __builtin_amdgcn_global_load_lds(
            (const __attribute__((address_space(1))) void*)(bt + b_go1),
            (__attribute__((address_space(3))) void*)(base + 16384 + seg_l1), 16, 0, 0);
    };
    auto compute = [&](int d) {
        const char* ab = &lds[d * 32768];
        const char* bb = ab + 16384;
        half8 bf[4];
#pragma unroll
        for (int j = 0; j < 4; ++j)
            bf[j] = *(const half8*)(bb + boff + j * 256);
#pragma unroll
        for (int p = 0; p < 4; ++p) {
            half8 a0 = *(const half8*)(ab + aoff + (2 * p) * 256);
            half8 a1 = *(const half8*)(ab + aoff + (2 * p + 1) * 256);
            __builtin_amdgcn_s_setprio(1);
#pragma unroll
            for (int j = 0; j < 4; ++j) {
                acc[2 * p][j]     = __builtin_amdgcn_mfma_f32_16x16x32_f16(a0, bf[j], acc[2 * p][j], 0, 0, 0);
                acc[2 * p + 1][j] = __builtin_amdgcn_mfma_f32_16x16x32_f16(a1, bf[j], acc[2 * p + 1][j], 0, 0, 0);
            }
            __builtin_amdgcn_s_setprio(0);
        }
    };
    auto step = [&](int d, int tstage) {
        asm volatile("s_waitcnt vmcnt(8)" ::: "memory");   // own tile-t loads done; 8 in flight
        __builtin_amdgcn_s_barrier();                      // all waves' tile-t staging done
        compute(d);
        __builtin_amdgcn_s_barrier();                      // all reads of buf d retired
        stage(d, tstage);                                  // tile t+3 (clamped) -> buf d
    };

    // prologue: fill 3 buffers
    stage(0, 0);
    stage(1, 1);
    stage(2, 2);

    for (int tt = 0; tt < 42; ++tt) {
        const int t = tt * 3;
        int t3 = t + 3; if (t3 > 127) t3 = 127;
        int t4 = t + 4; if (t4 > 127) t4 = 127;
        int t5 = t + 5; if (t5 > 127) t5 = 127;
        step(0, t3);
        step(1, t4);
        step(2, t5);
    }
    // t = 126 (buf 0): outstanding = t126, t127, dummy -> vmcnt(8) waits t126
    asm volatile("s_waitcnt vmcnt(8)" ::: "memory");
    __builtin_amdgcn_s_barrier();
    compute(0);
    // t = 127 (buf 1): outstanding = t127, dummy -> vmcnt(4) waits t127
    asm volatile("s_waitcnt vmcnt(4)" ::: "memory");
    __builtin_amdgcn_s_barrier();
    compute(1);

    // epilogue: C/D col = lane&15, row = (lane>>4)*4 + r ; non-temporal stores
    const int colb = n0 + wc * 64 + lm;
    const int rowb = m0 + wr * 128 + (kb_l << 2);
#pragma unroll
    for (int j = 0; j < 4; ++j) {
        const int col = colb + j * 16;
        const float bias_f = bias[col];
#pragma unroll
        for (int i = 0; i < 8; ++i) {
            const int row = rowb + i * 16;
#pragma unroll
            for (int r4 = 0; r4 < 4; ++r4) {
                __builtin_nontemporal_store(acc[i][j][r4] + bias_f,
                                            &out[(size_t)(row + r4) * N_DIM + col]);
            }
        }
    }
    // drain in-flight dummy gl_lds before block teardown
    asm volatile("s_waitcnt vmcnt(0) lgkmcnt(0)" ::: "memory");
}

// ================= R8 fused kernel (fallback when ws too small) =================
template <bool PRECVT>
__global__ __launch_bounds__(256, 3)
void awq_gemm5(const float* __restrict__ xf,
               const unsigned short* __restrict__ xb,
               const int* __restrict__ qweight,
               const int* __restrict__ qzeros,
               const float* __restrict__ scales,
               const float* __restrict__ bias,
               float* __restrict__ out)
{
    __shared__ char lds[32768] __attribute__((aligned(128)));
    const int tid  = threadIdx.x;
    const int lane = tid & 63;
    const int wid  = tid >> 6;
    const int n0 = blockIdx.x * BN;
    const int m0 = blockIdx.y * BM;

    const unsigned short* agl0 = xb + (size_t)(m0 + lane) * K_DIM + wid * 8;
    const unsigned short* agl1 = xb + (size_t)(m0 + 64 + lane) * K_DIM + wid * 8;
    const float* aptr = xf + (size_t)(m0 + (tid >> 1)) * K_DIM + (tid & 1) * 16;
    const int awr = ((tid & 1) * 2) * 2048 + (tid >> 1) * 16;

    const int nq      = tid & 15;
    const int k_local = (tid >> 4) * 2;
    const int kb_w    = k_local >> 3;
    const int k8      = k_local & 7;
    const int nq7     = nq & 7;
    const int* qp0 = qweight + blockIdx.x * 16 + nq + (size_t)k_local * NQ_DIM;
    const int* qp1 = qp0 + NQ_DIM;
    const int* zp  = qzeros + blockIdx.x * 16 + nq;
    const float* sp = scales + n0 + nq * 8;
    int baddr[8];
#pragma unroll
    for (int j = 0; j < 8; ++j)
        baddr[j] = 16384 + (kb_w * 128 + nq * 8 + (j ^ nq7)) * 16 + k8 * 2;

    const int wm = (wid >> 1) * 64;
    const int wn = (wid & 1) * 64;
    const int lm = lane & 15;
    const int kb_l = lane >> 4;
    const int aoff = kb_l * 2048 + (wm + lm) * 16;
    int boff[4];
#pragma unroll
    for (int j = 0; j < 4; ++j) {
        int blk = kb_l * 128 + wn + j * 16 + lm;
        blk ^= (blk >> 3) & 7;
        boff[j] = 16384 + blk * 16;
    }

    floatx4 acc[4][4];
#pragma unroll
    for (int i = 0; i < 4; ++i)
#pragma unroll
        for (int j = 0; j < 4; ++j)
            acc[i][j] = (floatx4){0.f, 0.f, 0.f, 0.f};

    half2v zt[4], st[4];
    uint32_t q0, q1;

    auto stage_a = [&](int abase) {
        if constexpr (PRECVT) {
            __builtin_amdgcn_global_load_lds(
                (const __attribute__((address_space(1))) void*)agl0,
                (__attribute__((address_space(3))) void*)(&lds[abase + wid * 2048]), 16, 0, 0);
            __builtin_amdgcn_global_load_lds(
                (const __attribute__((address_space(1))) void*)agl1,
                (__attribute__((address_space(3))) void*)(&lds[abase + wid * 2048 + 1024]), 16, 0, 0);
            agl0 += BK; agl1 += BK;
        } else {
            floatx4 a0 = *(const floatx4*)(aptr + 0);
            floatx4 a1 = *(const floatx4*)(aptr + 4);
            floatx4 a2 = *(const floatx4*)(aptr + 8);
            floatx4 a3 = *(const floatx4*)(aptr + 12);
            aptr += BK;
            union { short8 v; uint32_t u[4]; } o0, o1;
            o0.u[0] = pkh(a0[0], a0[1]); o0.u[1] = pkh(a0[2], a0[3]);
            o0.u[2] = pkh(a1[0], a1[1]); o0.u[3] = pkh(a1[2], a1[3]);
            o1.u[0] = pkh(a2[0], a2[1]); o1.u[1] = pkh(a2[2], a2[3]);
            o1.u[2] = pkh(a3[0], a3[1]); o1.u[3] = pkh(a3[2], a3[3]);
            *(short8*)&lds[abase + awr]        = o0.v;
            *(short8*)&lds[abase + awr + 2048] = o1.v;
        }
    };
    auto load_q = [&]() {
        q0 = (uint32_t)*qp0; q1 = (uint32_t)*qp1;
        qp0 += (size_t)BK * NQ_DIM; qp1 += (size_t)BK * NQ_DIM;
    };
    auto refresh = [&]() {
        const uint32_t zw = (uint32_t)*zp;
        zp += NQ_DIM;
#pragma unroll
        for (int l = 0; l < 4; ++l) {
            zt[l] = u2h(((zw >> (4 * l)) & 0x000F000Fu) | 0x64006400u);
            float2v s2 = *(const float2v*)(sp + 2 * l);
            half2v sh2; sh2[0] = (_Float16)s2[0]; sh2[1] = (_Float16)s2[1];
            st[l] = sh2;
        }
        sp += N_DIM;
    };
    auto deq_store = [&](int off) {
#pragma unroll
        for (int l = 0; l < 4; ++l) {
            uint32_t t0 = ((q0 >> (4 * l)) & 0x000F000Fu) | 0x64006400u;
            uint32_t t1 = ((q1 >> (4 * l)) & 0x000F000Fu) | 0x64006400u;
            half2v w0 = (u2h(t0) - zt[l]) * st[l];
            half2v w1 = (u2h(t1) - zt[l]) * st[l];
            uint32_t p0 = h2u(w0), p1 = h2u(w1);
            uint32_t de = (p0 & 0xFFFFu) | (p1 << 16);
            uint32_t dd = (p0 >> 16) | (p1 & 0xFFFF0000u);
            *(uint32_t*)&lds[baddr[2 * l]     + off] = de;
            *(uint32_t*)&lds[baddr[2 * l + 1] + off] = dd;
        }
    };
    auto compute = [&](int ab, int bb) {
        half8 af[4], bfr[4];
#pragma unroll
        for (int i = 0; i < 4; ++i) af[i] = *(const half8*)&lds[ab + aoff + i * 256];
#pragma unroll
        for (int j = 0; j < 4; ++j) bfr[j] = *(const half8*)&lds[bb + boff[j] - 16384];
#pragma unroll
        for (int i = 0; i < 4; ++i)
#pragma unroll
            for (int j = 0; j < 4; ++j)
                acc[i][j] = __builtin_amdgcn_mfma_f32_16x16x32_f16(af[i], bfr[j], acc[i][j], 0, 0, 0);
    };

    stage_a(0); load_q(); refresh(); deq_store(0); load_q();
    __syncthreads();

    for (int t = 0; t < NSTEPS; t += 2) {
        stage_a(8192);
        deq_store(8192);
        if (t + 2 < NSTEPS) load_q();
        compute(0, 16384);
        __syncthreads();
        if (t + 2 < NSTEPS) {
            stage_a(0);
            if (((t + 2) & 3) == 0) refresh();
            deq_store(0);
            if (t + 3 < NSTEPS) load_q();
        }
        compute(8192, 24576);
        __syncthreads();
    }

    const int colb = n0 + wn + lm;
    const int rowb = m0 + wm + (kb_l << 2);
#pragma unroll
    for (int j = 0; j < 4; ++j) {
        const int col = colb + j * 16;
        const float bias_f = bias[col];
#pragma unroll
        for (int i = 0; i < 4; ++i) {
            const int row = rowb + i * 16;
#pragma unroll
            for (int r4 = 0; r4 < 4; ++r4) {
                out[(size_t)(row + r4) * N_DIM + col] = acc[i][j][r4] + bias_f;
            }
        }
    }
}

extern "C" void kernel_launch(void* const* d_in, const int* in_sizes, int n_in,
                              void* d_out, int out_size, void* d_ws, size_t ws_size,
                              hipStream_t stream) {
    const float* x    = (const float*)d_in[0];
    const int* qw     = (const int*)d_in[1];
    const int* qz     = (const int*)d_in[2];
    const float* sc   = (const float*)d_in[3];
    const float* bi   = (const float*)d_in[4];
    float* out        = (float*)d_out;

    const int M = in_sizes[0] / K_DIM;                       // 8192
    const size_t xb_bytes = (size_t)M * K_DIM * 2;           // 64 MiB
    const size_t wb_bytes = (size_t)K_DIM * N_DIM * 2;       // 86 MiB

    if (ws_size >= xb_bytes + wb_bytes) {
        unsigned short* xb = (unsigned short*)d_ws;
        unsigned short* wb = (unsigned short*)((char*)d_ws + xb_bytes);
        const int n8 = (int)((size_t)M * K_DIM / 8);
        cvt_x<<<2048, 256, 0, stream>>>(x, xb, n8);
        deq_w2<<<dim3(NT2, NSTEPS), 512, 0, stream>>>(qw, qz, sc, wb);
        awq_gemm9<<<dim3(NT2, M / 256), 512, 0, stream>>>(xb, wb, bi, out);
    } else if (ws_size >= xb_bytes) {
        unsigned short* xb = (unsigned short*)d_ws;
        const int n8 = (int)((size_t)M * K_DIM / 8);
        cvt_x<<<2048, 256, 0, stream>>>(x, xb, n8);
        awq_gemm5<true><<<dim3(NT_DIM, M / BM), 256, 0, stream>>>(x, xb, qw, qz, sc, bi, out);
    } else {
        awq_gemm5<false><<<dim3(NT_DIM, M / BM), 256, 0, stream>>>(x, nullptr, qw, qz, sc, bi, out);
    }
}